// Round 14
// baseline (1662.827 us; speedup 1.0000x reference)
//
#include <hip/hip_runtime.h>
#include <cmath>

#define EPSV 1e-20f
#define MFMA16(A, B, C) __builtin_amdgcn_mfma_f32_16x16x32_f16(A, B, C, 0, 0, 0)

typedef _Float16 f16;
typedef _Float16 v8h __attribute__((ext_vector_type(8)));
typedef _Float16 h4 __attribute__((ext_vector_type(4)));
typedef float v4f __attribute__((ext_vector_type(4)));

__device__ __forceinline__ float softplusf(float x) {
    return fmaxf(x, 0.f) + log1pf(expf(-fabsf(x)));
}

__device__ __forceinline__ v8h v8h_zero() {
    v8h z = {0, 0, 0, 0, 0, 0, 0, 0};
    return z;
}

// lane l <- lane l+16. MUST be called with all 64 lanes active (ds_bpermute
// reads from inactive lanes are undefined) — never call inside divergence.
__device__ __forceinline__ v8h shfl_dn16(v8h v) {
    union { v8h h; int i[4]; } u, r;
    u.h = v;
#pragma unroll
    for (int k = 0; k < 4; ++k) r.i[k] = __shfl_down(u.i[k], 16, 64);
    return r.h;
}

// ---------------------------------------------------------------------------
// Weight prep, merged. WT floats: s_l @ [200+(l-1)*8], wp7 @ 256.
// BF2/BF3: enc 5x5 frags. BF1: l1 frag.
// ---------------------------------------------------------------------------
__global__ void prep_misc(const float* __restrict__ w1, const float* __restrict__ w2,
                          const float* __restrict__ w3, const float* __restrict__ w4,
                          const float* __restrict__ w5, const float* __restrict__ w6,
                          const float* __restrict__ w7, float* __restrict__ WT,
                          f16* __restrict__ BF2, f16* __restrict__ BF3,
                          f16* __restrict__ BF1) {
    int t = blockIdx.x;
    if (t < 7) {
        __shared__ float lds[1600];
        const float* srcs[7] = {w1, w2, w3, w4, w5, w6, w7};
        const int ns[7]    = {200, 1600, 1600, 1152, 1152, 1152, 8};
        const int pers[7]  = {25, 200, 200, 144, 144, 144, 8};
        const int couts[7] = {8, 8, 8, 8, 8, 8, 1};
        const float* src = srcs[t];
        int n = ns[t];
        for (int i = threadIdx.x; i < n; i += blockDim.x) {
            float v = softplusf(src[i]);
            lds[i] = v;
            if (t == 6) WT[256 + i] = v;  // wp7
        }
        __syncthreads();
        if ((int)threadIdx.x < couts[t]) {
            float s = 0.f;
            int per = pers[t];
            for (int i = 0; i < per; ++i) s += lds[threadIdx.x * per + i];
            WT[200 + t * 8 + threadIdx.x] = s;
        }
    } else if (t < 9) {
        // enc frags: g<5:(kh=g,kw=sub)  g==5:(kh=sub,kw=4)  g==6:(4,4) sub0
        const float* w = (t == 8) ? w3 : w2;
        f16* dst = (t == 8) ? BF3 : BF2;
        for (int i = threadIdx.x; i < 7 * 64 * 8; i += blockDim.x) {
            int g = i >> 9;
            int l = (i >> 3) & 63;
            int j = i & 7;
            int co = l & 15, sub = l >> 4;
            float v = 0.f;
            if (co < 8) {
                int kh = 0, kw = 0;
                bool valid = true;
                if (g < 5) { kh = g; kw = sub; }
                else if (g == 5) { kh = sub; kw = 4; }
                else { kh = 4; kw = 4; valid = (sub == 0); }
                if (valid) v = softplusf(w[((co * 8 + j) * 5 + kh) * 5 + kw]);
            }
            dst[i] = (f16)v;
        }
    } else {
        // l1 frag (CIN=1): j<=4:(kh=j,kw=sub)  j==5:(kh=sub,kw=4)  j==6:(4,4) sub0
        for (int i = threadIdx.x; i < 512; i += blockDim.x) {
            int l = i >> 3, j = i & 7;
            int co = l & 15, sub = l >> 4;
            float v = 0.f;
            if (co < 8) {
                if (j <= 4) v = softplusf(w1[co * 25 + j * 5 + sub]);
                else if (j == 5) v = softplusf(w1[co * 25 + sub * 5 + 4]);
                else if (j == 6 && sub == 0) v = softplusf(w1[co * 25 + 24]);
            }
            BF1[i] = (f16)v;
        }
    }
}

// Decoder 3x3 16ci weight frags with S parity folding. kw = sub (sub 3 zero).
//  g0-2: R block kh=g ; g3 = S kh0 ; g4 = S kh1+kh2 ; g5 = S kh0+kh1 ; g6 = S kh2
__global__ void pack_dec_frag(const float* __restrict__ w4, const float* __restrict__ w5,
                              const float* __restrict__ w6,
                              f16* __restrict__ dst4, f16* __restrict__ dst5,
                              f16* __restrict__ dst6) {
    const float* ww[3] = {w4, w5, w6};
    f16* dd[3] = {dst4, dst5, dst6};
    const int RBt[3] = {0, 0, 1};
    const float* w = ww[blockIdx.x];
    f16* dst = dd[blockIdx.x];
    const int rb = RBt[blockIdx.x], sbk = 1 - rb;
    for (int i = threadIdx.x; i < 7 * 64 * 8; i += blockDim.x) {
        int g = i >> 9;
        int l = (i >> 3) & 63;
        int j = i & 7;
        int co = l & 15, sub = l >> 4;
        float v = 0.f;
        if (co < 8 && sub < 3) {
            int kw = sub;
            auto W_ = [&](int blk, int kh) {
                return softplusf(w[((co * 16 + blk * 8 + j) * 3 + kh) * 3 + kw]);
            };
            if (g < 3) v = W_(rb, g);
            else if (g == 3) v = W_(sbk, 0);
            else if (g == 4) v = W_(sbk, 1) + W_(sbk, 2);
            else if (g == 5) v = W_(sbk, 0) + W_(sbk, 1);
            else v = W_(sbk, 2);
        }
        dst[i] = (f16)v;
    }
}

// ---------------------------------------------------------------------------
// Layer 1 via MFMA (CIN=1): fp32 planar (x,c) -> f16 NHWC (xc, c).
// ---------------------------------------------------------------------------
__global__ void __launch_bounds__(256) l1_mfma(
    const float* __restrict__ x0, const float* __restrict__ c0,
    const f16* __restrict__ afrag, const float* __restrict__ ssum,
    const float* __restrict__ bias,
    f16* __restrict__ xcout, f16* __restrict__ cout,
    int B, int H, int W, int CH) {
    const int lane = threadIdx.x & 63;
    const int wid = threadIdx.x >> 6;
    const int m = lane & 15, sub = lane >> 4;
    const int tilesW = (W + 15) >> 4;
    const int tw = blockIdx.x * 4 + wid;
    if (tw >= tilesW) return;
    const int w0 = tw << 4;
    const int b = blockIdx.z;
    const int h0 = blockIdx.y * CH;
    if (h0 >= H) return;

    v8h af = *(const v8h*)(afrag + lane * 8);

    float4 ssv = {1.f, 1.f, 1.f, 1.f}, bbv = {0.f, 0.f, 0.f, 0.f};
    if (sub < 2) {
        ssv = *(const float4*)(ssum + sub * 4);
        bbv = *(const float4*)(bias + sub * 4);
    }
    float rssv[4];
#pragma unroll
    for (int j = 0; j < 4; ++j) rssv[j] = __builtin_amdgcn_rcpf(((const float*)&ssv)[j]);

    const int HW = H * W;
    const float* cb = c0 + (size_t)b * HW;
    const float* xb = x0 + (size_t)b * HW;

    const unsigned W8u = (unsigned)W * 8;
    const unsigned bb8 = (unsigned)(b * H) * W8u;
    unsigned sbase = bb8 + (unsigned)h0 * W8u + (unsigned)(w0 + m) * 8 + sub * 4;

    auto epi = [&](const v4f& accd, const v4f& accn) {
        h4 xo8, c8;
#pragma unroll
        for (int j = 0; j < 4; ++j) {
            float d = accd[j];
            float cc = d * rssv[j];
            float x = accn[j] * __builtin_amdgcn_rcpf(d + EPSV) + ((const float*)&bbv)[j];
            c8[j] = (f16)cc;
            xo8[j] = (f16)(x * cc);
        }
        *(h4*)(cout + sbase) = c8;
        *(h4*)(xcout + sbase) = xo8;
    };

    const int colr = w0 + m + sub - 2;
    const int cole = w0 + m + 2;

    const bool fast = (w0 >= 2) && (w0 + 17 < W) && (h0 >= 2) && (h0 + CH + 2 <= H);
    if (fast) {
        const float* crow = cb + (size_t)(h0 - 2) * W + colr;
        const float* xrow = xb + (size_t)(h0 - 2) * W + colr;
        f16 rc[5], rx[5];
#pragma unroll
        for (int t = 0; t < 4; ++t) {
            float cv = *crow, xv = *xrow;
            crow += W; xrow += W;
            rc[t] = (f16)cv;
            rx[t] = (f16)(xv * cv);
        }
        rc[4] = (f16)0; rx[4] = (f16)0;
        const float* c5p = cb + (size_t)(h0 + sub - 2) * W + cole;
        const float* x5p = xb + (size_t)(h0 + sub - 2) * W + cole;
        const float* c6p = cb + (size_t)(h0 + 2) * W + cole;
        const float* x6p = xb + (size_t)(h0 + 2) * W + cole;
        const bool st = (sub < 2);
        for (int hh = 0; hh < CH; hh += 5) {
#pragma unroll
            for (int p = 0; p < 5; ++p) {
                float cv = *crow, xv = *xrow;
                crow += W; xrow += W;
                rc[(p + 4) % 5] = (f16)cv;
                rx[(p + 4) % 5] = (f16)(xv * cv);
                float c5 = *c5p, x5 = *x5p;
                c5p += W; x5p += W;
                float c6 = *c6p, x6 = *x6p;
                c6p += W; x6p += W;
                f16 e5c = (f16)c5, e5x = (f16)(x5 * c5);
                f16 e6c = (f16)c6, e6x = (f16)(x6 * c6);
                v8h bc = {rc[p % 5], rc[(p + 1) % 5], rc[(p + 2) % 5],
                          rc[(p + 3) % 5], rc[(p + 4) % 5], e5c, e6c, (f16)0};
                v8h bx = {rx[p % 5], rx[(p + 1) % 5], rx[(p + 2) % 5],
                          rx[(p + 3) % 5], rx[(p + 4) % 5], e5x, e6x, (f16)0};
                v4f z = {0.f, 0.f, 0.f, 0.f};
                v4f accd = MFMA16(af, bc, z);
                v4f accn = MFMA16(af, bx, z);
                if (st) epi(accd, accn);
                sbase += W8u;
            }
        }
    } else {
        const bool okr = (colr >= 0) && (colr < W);
        const bool oke = (cole < W);
        const int colrc = min(max(colr, 0), W - 1);
        const int colec = min(cole, W - 1);
        const bool st = (sub < 2) && (w0 + m < W);
        for (int hh = 0; hh < CH; ++hh) {
            const int h = h0 + hh;
            if (h >= H) break;
            f16 vc[8], vx[8];
#pragma unroll
            for (int j = 0; j < 5; ++j) {
                int r = h + j - 2;
                bool ok = okr && (r >= 0) && (r < H);
                int rcl = min(max(r, 0), H - 1);
                float cv = cb[(size_t)rcl * W + colrc];
                float xv = xb[(size_t)rcl * W + colrc];
                vc[j] = ok ? (f16)cv : (f16)0;
                vx[j] = ok ? (f16)(xv * cv) : (f16)0;
            }
            {
                int r = h + sub - 2;
                bool ok = oke && (r >= 0) && (r < H);
                int rcl = min(max(r, 0), H - 1);
                float cv = cb[(size_t)rcl * W + colec];
                float xv = xb[(size_t)rcl * W + colec];
                vc[5] = ok ? (f16)cv : (f16)0;
                vx[5] = ok ? (f16)(xv * cv) : (f16)0;
            }
            {
                int r = h + 2;
                bool ok = oke && (r < H);
                int rcl = min(r, H - 1);
                float cv = cb[(size_t)rcl * W + colec];
                float xv = xb[(size_t)rcl * W + colec];
                vc[6] = ok ? (f16)cv : (f16)0;
                vx[6] = ok ? (f16)(xv * cv) : (f16)0;
            }
            vc[7] = (f16)0; vx[7] = (f16)0;
            v8h bc = {vc[0], vc[1], vc[2], vc[3], vc[4], vc[5], vc[6], vc[7]};
            v8h bx = {vx[0], vx[1], vx[2], vx[3], vx[4], vx[5], vx[6], vx[7]};
            v4f z = {0.f, 0.f, 0.f, 0.f};
            v4f accd = MFMA16(af, bc, z);
            v4f accn = MFMA16(af, bx, z);
            if (st) epi(accd, accn);
            sbase += W8u;
        }
    }
}

// ---------------------------------------------------------------------------
// Pool-gather NHWC, 2 output pixels per thread.
// ---------------------------------------------------------------------------
__global__ void __launch_bounds__(256) pool_nhwc(
    const f16* __restrict__ xc, const f16* __restrict__ c,
    f16* __restrict__ xo, f16* __restrict__ co_,
    int B, int H, int W) {
    int H2 = H >> 1, W2 = W >> 1, Wh = W2 >> 1;
    int idx = blockIdx.x * 256 + threadIdx.x;
    int total = B * H2 * Wh;
    if (idx >= total) return;
    int wo = (idx % Wh) * 2;
    int ho = (idx / Wh) % H2;
    int b = idx / (Wh * H2);
    unsigned base = (unsigned)(((b * H + 2 * ho) * W + 2 * wo) * 8);
    unsigned rb = (unsigned)(W * 8);
    v8h c0r[4], c1r[4], x0r[4], x1r[4];
#pragma unroll
    for (int i = 0; i < 4; ++i) {
        c0r[i] = *(const v8h*)(c + base + 8 * i);
        c1r[i] = *(const v8h*)(c + base + rb + 8 * i);
        x0r[i] = *(const v8h*)(xc + base + 8 * i);
        x1r[i] = *(const v8h*)(xc + base + rb + 8 * i);
    }
    unsigned oa = (unsigned)(((b * H2 + ho) * W2 + wo) * 8);
#pragma unroll
    for (int p = 0; p < 2; ++p) {
        v8h xr, cr;
#pragma unroll
        for (int e = 0; e < 8; ++e) {
            float b0 = (float)c0r[2 * p][e], b1 = (float)c0r[2 * p + 1][e];
            float b2 = (float)c1r[2 * p][e], b3 = (float)c1r[2 * p + 1][e];
            float cb = b0;
            float xv = (float)x0r[2 * p][e];
            if (b1 > cb) { cb = b1; xv = (float)x0r[2 * p + 1][e]; }
            if (b2 > cb) { cb = b2; xv = (float)x1r[2 * p][e]; }
            if (b3 > cb) { cb = b3; xv = (float)x1r[2 * p + 1][e]; }
            xr[e] = (f16)(xv * 0.25f);
            cr[e] = (f16)(cb * 0.25f);
        }
        *(v8h*)(xo + oa + p * 8) = xr;
        *(v8h*)(co_ + oa + p * 8) = cr;
    }
}

// ---------------------------------------------------------------------------
// Encoder nconv via MFMA. Fast path: 5-ring rotation + E5 cross-lane rotation
// (shfl executed with full exec, then per-lane select). 4 loads/row.
// __launch_bounds__(256, 8): force <=64 VGPR (8 waves/SIMD residency tier —
// the E5 rotation pushed the allocator to 68 and occupancy fell 35->25%).
// CH multiple of 5.
// ---------------------------------------------------------------------------
__global__ void __launch_bounds__(256, 8) enc5_mfma(
    const f16* __restrict__ xcin, const f16* __restrict__ cin,
    const f16* __restrict__ bfrag, const float* __restrict__ ssum,
    const float* __restrict__ bias,
    f16* __restrict__ xcout, f16* __restrict__ cout,
    int B, int H, int W, int CH) {
    const int lane = threadIdx.x & 63;
    const int wid = threadIdx.x >> 6;
    const int m = lane & 15, sub = lane >> 4;
    const int tilesW = (W + 15) >> 4;
    const int tw = blockIdx.x * 4 + wid;
    if (tw >= tilesW) return;
    const int w0 = tw << 4;
    const int b = blockIdx.z;
    const int h0 = blockIdx.y * CH;
    if (h0 >= H) return;

    v8h bf[7];
#pragma unroll
    for (int g = 0; g < 7; ++g)
        bf[g] = *(const v8h*)(bfrag + ((g << 6) + lane) * 8);

    float4 ssv = {1.f, 1.f, 1.f, 1.f}, bbv = {0.f, 0.f, 0.f, 0.f};
    if (sub < 2) {
        ssv = *(const float4*)(ssum + sub * 4);
        bbv = *(const float4*)(bias + sub * 4);
    }
    float rssv[4];
#pragma unroll
    for (int j = 0; j < 4; ++j) rssv[j] = __builtin_amdgcn_rcpf(((const float*)&ssv)[j]);

    const unsigned W8u = (unsigned)W * 8;
    const unsigned bb8 = (unsigned)(b * H) * W8u;
    unsigned sbase = bb8 + (unsigned)h0 * W8u + (unsigned)(w0 + m) * 8 + sub * 4;

    auto epi = [&](const v4f& accd, const v4f& accn) {
        h4 xo8, c8;
#pragma unroll
        for (int j = 0; j < 4; ++j) {
            float d = accd[j];
            float cc = d * rssv[j];
            float x = accn[j] * __builtin_amdgcn_rcpf(d + EPSV) + ((const float*)&bbv)[j];
            c8[j] = (f16)cc;
            xo8[j] = (f16)(x * cc);
        }
        *(h4*)(cout + sbase) = c8;
        *(h4*)(xcout + sbase) = xo8;
    };

    const bool fast = (w0 >= 2) && (w0 + 17 < W) && (h0 >= 2) && (h0 + CH + 2 <= H);
    if (fast) {
        v8h Rc[5], Rx[5];
        unsigned aRot = bb8 + (unsigned)(h0 - 2) * W8u + (unsigned)(w0 + m + sub - 2) * 8;
#pragma unroll
        for (int t = 0; t < 4; ++t) {
            Rc[t] = *(const v8h*)(cin + aRot);
            Rx[t] = *(const v8h*)(xcin + aRot);
            aRot += W8u;
        }
        // E5 warm-up: row h0+sub-2, col w0+m+2
        unsigned aE5w = bb8 + (unsigned)(h0 + sub - 2) * W8u + (unsigned)(w0 + m + 2) * 8;
        v8h E5c = *(const v8h*)(cin + aE5w);
        v8h E5x = *(const v8h*)(xcin + aE5w);
        unsigned aE6 = bb8 + (unsigned)(h0 + 2) * W8u + (unsigned)(w0 + m + 2) * 8;
        const bool st = (sub < 2);
        for (int hh = 0; hh < CH; hh += 5) {
#pragma unroll
            for (int p = 0; p < 5; ++p) {
                Rc[(p + 4) % 5] = *(const v8h*)(cin + aRot);
                Rx[(p + 4) % 5] = *(const v8h*)(xcin + aRot);
                aRot += W8u;
                v8h e6c = *(const v8h*)(cin + aE6);
                v8h e6x = *(const v8h*)(xcin + aE6);
                aE6 += W8u;

                v4f accd = {0.f, 0.f, 0.f, 0.f}, accn = {0.f, 0.f, 0.f, 0.f};
#pragma unroll
                for (int g = 0; g < 5; ++g) {
                    accd = MFMA16(bf[g], Rc[(p + g) % 5], accd);
                    accn = MFMA16(bf[g], Rx[(p + g) % 5], accn);
                }
                accd = MFMA16(bf[5], E5c, accd);
                accn = MFMA16(bf[5], E5x, accn);
                accd = MFMA16(bf[6], e6c, accd);
                accn = MFMA16(bf[6], e6x, accn);

                // rotate E5 for next row: shfl with FULL exec, then select.
                v8h rotc = shfl_dn16(E5c);
                v8h rotx = shfl_dn16(E5x);
                E5c = (sub < 3) ? rotc : e6c;
                E5x = (sub < 3) ? rotx : e6x;

                if (st) epi(accd, accn);
                sbase += W8u;
            }
        }
    } else {
        const int cwr = w0 + m + sub - 2;
        const bool okc_r = (cwr >= 0) && (cwr < W);
        const unsigned a_rot = (unsigned)min(max(cwr, 0), W - 1) * 8;
        const int cwe = w0 + m + 2;
        const bool okc_e = cwe < W;
        const unsigned a_e = (unsigned)min(cwe, W - 1) * 8;
        const bool doStore = (sub < 2) && (w0 + m < W);

        v8h Rc[5], Rx[5];
#pragma unroll
        for (int t = 0; t < 4; ++t) {
            int r = h0 - 2 + t;
            bool ok = (r >= 0) && (r < H) && okc_r;
            unsigned a = bb8 + (unsigned)min(max(r, 0), H - 1) * W8u + a_rot;
            v8h pc = *(const v8h*)(cin + a);
            v8h px = *(const v8h*)(xcin + a);
            Rc[t] = ok ? pc : v8h_zero();
            Rx[t] = ok ? px : v8h_zero();
        }
        Rc[4] = v8h_zero();
        Rx[4] = v8h_zero();

        for (int hh = 0; hh < CH; hh += 5) {
#pragma unroll
            for (int p = 0; p < 5; ++p) {
                const int h = h0 + hh + p;
                {
                    int r = h + 2;
                    bool ok = (r < H) && okc_r;
                    unsigned a = bb8 + (unsigned)min(r, H - 1) * W8u + a_rot;
                    v8h pc = *(const v8h*)(cin + a);
                    v8h px = *(const v8h*)(xcin + a);
                    Rc[(p + 4) % 5] = ok ? pc : v8h_zero();
                    Rx[(p + 4) % 5] = ok ? px : v8h_zero();
                }
                v8h e5c, e5x;
                {
                    int r = h + sub - 2;
                    bool ok = (r >= 0) && (r < H) && okc_e;
                    unsigned a = bb8 + (unsigned)min(max(r, 0), H - 1) * W8u + a_e;
                    v8h pc = *(const v8h*)(cin + a);
                    v8h px = *(const v8h*)(xcin + a);
                    e5c = ok ? pc : v8h_zero();
                    e5x = ok ? px : v8h_zero();
                }
                v8h e6c, e6x;
                {
                    int r = h + 2;
                    bool ok = (r < H) && okc_e;
                    unsigned a = bb8 + (unsigned)min(r, H - 1) * W8u + a_e;
                    v8h pc = *(const v8h*)(cin + a);
                    v8h px = *(const v8h*)(xcin + a);
                    e6c = ok ? pc : v8h_zero();
                    e6x = ok ? px : v8h_zero();
                }

                v4f accd = {0.f, 0.f, 0.f, 0.f}, accn = {0.f, 0.f, 0.f, 0.f};
#pragma unroll
                for (int g = 0; g < 5; ++g) {
                    accd = MFMA16(bf[g], Rc[(p + g) % 5], accd);
                    accn = MFMA16(bf[g], Rx[(p + g) % 5], accn);
                }
                accd = MFMA16(bf[5], e5c, accd);
                accn = MFMA16(bf[5], e5x, accn);
                accd = MFMA16(bf[6], e6c, accd);
                accn = MFMA16(bf[6], e6x, accn);

                if (doStore && h < H) epi(accd, accn);
                sbase += W8u;
            }
        }
    }
}

// ---------------------------------------------------------------------------
// Decoder nconv via MFMA (round-10 verified): R = same-res source (bf 0-2,
// rotating ring 3), S = half-res source with parity-folded weights (bf 3-6).
// CH multiple of 6, h0 even. FUSE7: fused final 1x1 nconv, fp32 1-ch outputs.
// ---------------------------------------------------------------------------
template <bool FUSE7>
__global__ void __launch_bounds__(256) dec3_mfma(
    const f16* __restrict__ xcR, const f16* __restrict__ cR,
    const f16* __restrict__ xcS, const f16* __restrict__ cS,
    const f16* __restrict__ bfrag,
    const float* __restrict__ ssum, const float* __restrict__ bias,
    const float* __restrict__ wp7, const float* __restrict__ s7p,
    const float* __restrict__ b7p,
    f16* __restrict__ xcout, f16* __restrict__ ccout,
    float* __restrict__ xoutf, float* __restrict__ coutf,
    int B, int H, int W, int CH) {
    const int lane = threadIdx.x & 63;
    const int wid = threadIdx.x >> 6;
    const int m = lane & 15, sub = lane >> 4;
    const int tilesW = W >> 4;
    const int tw = blockIdx.x * 4 + wid;
    if (tw >= tilesW) return;
    const int w0 = tw << 4;
    const int b = blockIdx.z;
    const int h0 = blockIdx.y * CH;
    if (h0 >= H) return;

    v8h bf[7];
#pragma unroll
    for (int g = 0; g < 7; ++g)
        bf[g] = *(const v8h*)(bfrag + ((g << 6) + lane) * 8);

    const int cw = w0 + m + sub - 1;
    const bool okc = (cw >= 0) && (cw < W);
    const int cwc = min(max(cw, 0), W - 1);
    const unsigned aRc = (unsigned)cwc * 8;
    const unsigned aSc = (unsigned)(cwc >> 1) * 8;

    const int Hs = H >> 1, Ws = W >> 1;
    const unsigned WR8 = (unsigned)W * 8;
    const unsigned WS8 = (unsigned)Ws * 8;
    const unsigned bbR = (unsigned)(b * H) * WR8;
    const unsigned bbS = (unsigned)(b * Hs) * WS8;

    float4 ssv = {1.f, 1.f, 1.f, 1.f}, bbv = {0.f, 0.f, 0.f, 0.f};
    float4 w7v = {0.f, 0.f, 0.f, 0.f};
    if (sub < 2) {
        ssv = *(const float4*)(ssum + sub * 4);
        bbv = *(const float4*)(bias + sub * 4);
        if (FUSE7) w7v = *(const float4*)(wp7 + sub * 4);
    }
    float rssv[4];
#pragma unroll
    for (int j = 0; j < 4; ++j) rssv[j] = __builtin_amdgcn_rcpf(((const float*)&ssv)[j]);
    float rs7 = 0.f, b7v = 0.f;
    if (FUSE7) { rs7 = __builtin_amdgcn_rcpf(s7p[0]); b7v = b7p[0]; }

    unsigned sbase = bbR + (unsigned)h0 * WR8 + (unsigned)(w0 + m) * 8 + sub * 4;
    unsigned opix = (unsigned)(b * H + h0) * (unsigned)W + (unsigned)w0;

    auto epi = [&](const v4f& accd, const v4f& accn) {
        if constexpr (FUSE7) {
            float td = 0.f, tn = 0.f;
#pragma unroll
            for (int j = 0; j < 4; ++j) {
                float d = accd[j];  // exactly 0 for co>=8 (weights zeroed)
                float cc = d * rssv[j];
                float o = accn[j] * __builtin_amdgcn_rcpf(d + EPSV) + ((const float*)&bbv)[j];
                td = fmaf(((const float*)&w7v)[j], cc, td);
                tn = fmaf(((const float*)&w7v)[j], o * cc, tn);
            }
            td += __shfl_xor(td, 16);
            tn += __shfl_xor(tn, 16);
            td += __shfl_xor(td, 32);
            tn += __shfl_xor(tn, 32);
            if (sub == 0) {
                xoutf[opix + m] = tn * __builtin_amdgcn_rcpf(td + EPSV) + b7v;
            } else if (sub == 1) {
                coutf[opix + m] = td * rs7;
            }
        } else {
            if (sub < 2) {
                h4 xo8, c8;
#pragma unroll
                for (int j = 0; j < 4; ++j) {
                    float d = accd[j];
                    float cc = d * rssv[j];
                    float x = accn[j] * __builtin_amdgcn_rcpf(d + EPSV) + ((const float*)&bbv)[j];
                    c8[j] = (f16)cc;
                    xo8[j] = (f16)(x * cc);
                }
                *(h4*)(ccout + sbase) = c8;
                *(h4*)(xcout + sbase) = xo8;
            }
        }
    };

    const bool fast = (w0 >= 1) && (w0 + 17 < W) && (h0 >= 2) && (h0 + CH + 1 <= H);
    if (fast) {
        v8h Rc_[3], Rx_[3], Sc_[3], Sx_[3];
        unsigned ar = bbR + (unsigned)(h0 - 1) * WR8 + aRc;
        Rc_[2] = *(const v8h*)(cR + ar); Rx_[2] = *(const v8h*)(xcR + ar); ar += WR8;
        Rc_[0] = *(const v8h*)(cR + ar); Rx_[0] = *(const v8h*)(xcR + ar); ar += WR8;
        const int k0 = h0 >> 1;
        unsigned as_ = bbS + (unsigned)(k0 - 1) * WS8 + aSc;
        Sc_[2] = *(const v8h*)(cS + as_); Sx_[2] = *(const v8h*)(xcS + as_); as_ += WS8;
        Sc_[0] = *(const v8h*)(cS + as_); Sx_[0] = *(const v8h*)(xcS + as_); as_ += WS8;

        for (int hh = 0; hh < CH; hh += 6) {
#pragma unroll
            for (int p = 0; p < 6; ++p) {
                const int j = p >> 1;
                Rc_[(p + 1) % 3] = *(const v8h*)(cR + ar);
                Rx_[(p + 1) % 3] = *(const v8h*)(xcR + ar);
                ar += WR8;
                if ((p & 1) == 0) {  // prefetch S row k+1
                    Sc_[(j + 1) % 3] = *(const v8h*)(cS + as_);
                    Sx_[(j + 1) % 3] = *(const v8h*)(xcS + as_);
                    as_ += WS8;
                }
                v4f accd = {0.f, 0.f, 0.f, 0.f}, accn = {0.f, 0.f, 0.f, 0.f};
#pragma unroll
                for (int g = 0; g < 3; ++g) {
                    accd = MFMA16(bf[g], Rc_[(p + g + 2) % 3], accd);
                    accn = MFMA16(bf[g], Rx_[(p + g + 2) % 3], accn);
                }
                if ((p & 1) == 0) {  // even h: W0 on S[k-1], W12 on S[k]
                    accd = MFMA16(bf[3], Sc_[(j + 2) % 3], accd);
                    accn = MFMA16(bf[3], Sx_[(j + 2) % 3], accn);
                    accd = MFMA16(bf[4], Sc_[j % 3], accd);
                    accn = MFMA16(bf[4], Sx_[j % 3], accn);
                } else {             // odd h: W01 on S[k], W2 on S[k+1]
                    accd = MFMA16(bf[5], Sc_[j % 3], accd);
                    accn = MFMA16(bf[5], Sx_[j % 3], accn);
                    accd = MFMA16(bf[6], Sc_[(j + 1) % 3], accd);
                    accn = MFMA16(bf[6], Sx_[(j + 1) % 3], accn);
                }
                epi(accd, accn);
                sbase += WR8;
                opix += W;
            }
        }
    } else {
        for (int hh = 0; hh < CH; ++hh) {
            const int h = h0 + hh;
            if (h >= H) break;
            const int k = h >> 1;
            const bool ev = (h & 1) == 0;
            v4f accd = {0.f, 0.f, 0.f, 0.f}, accn = {0.f, 0.f, 0.f, 0.f};
#pragma unroll
            for (int g = 0; g < 3; ++g) {
                int r = h + g - 1;
                bool ok = okc && (r >= 0) && (r < H);
                unsigned a = bbR + (unsigned)min(max(r, 0), H - 1) * WR8 + aRc;
                v8h pc = *(const v8h*)(cR + a);
                v8h px = *(const v8h*)(xcR + a);
                if (!ok) { pc = v8h_zero(); px = v8h_zero(); }
                accd = MFMA16(bf[g], pc, accd);
                accn = MFMA16(bf[g], px, accn);
            }
            {
                int rs = ev ? (k - 1) : k;
                bool ok = okc && (!ev || (h >= 1));
                unsigned a = bbS + (unsigned)min(max(rs, 0), Hs - 1) * WS8 + aSc;
                v8h pc = *(const v8h*)(cS + a);
                v8h px = *(const v8h*)(xcS + a);
                if (!ok) { pc = v8h_zero(); px = v8h_zero(); }
                v8h wA = ev ? bf[3] : bf[5];
                accd = MFMA16(wA, pc, accd);
                accn = MFMA16(wA, px, accn);
            }
            {
                int rs = ev ? k : (k + 1);
                bool ok = okc && (ev || (h + 1 < H));
                unsigned a = bbS + (unsigned)min(max(rs, 0), Hs - 1) * WS8 + aSc;
                v8h pc = *(const v8h*)(cS + a);
                v8h px = *(const v8h*)(xcS + a);
                if (!ok) { pc = v8h_zero(); px = v8h_zero(); }
                v8h wB = ev ? bf[4] : bf[6];
                accd = MFMA16(wB, pc, accd);
                accn = MFMA16(wB, px, accn);
            }
            epi(accd, accn);
            sbase += WR8;
            opix += W;
        }
    }
}

// ---------------------------------------------------------------------------
extern "C" void kernel_launch(void* const* d_in, const int* in_sizes, int n_in,
                              void* d_out, int out_size, void* d_ws, size_t ws_size,
                              hipStream_t stream) {
    const float* x0 = (const float*)d_in[0];
    const float* c0 = (const float*)d_in[1];
    const float* w1 = (const float*)d_in[2];
    const float* b1 = (const float*)d_in[3];
    const float* w2 = (const float*)d_in[4];
    const float* b2 = (const float*)d_in[5];
    const float* w3 = (const float*)d_in[6];
    const float* b3 = (const float*)d_in[7];
    const float* w4 = (const float*)d_in[8];
    const float* b4 = (const float*)d_in[9];
    const float* w5 = (const float*)d_in[10];
    const float* b5 = (const float*)d_in[11];
    const float* w6 = (const float*)d_in[12];
    const float* b6 = (const float*)d_in[13];
    const float* w7 = (const float*)d_in[14];
    const float* b7 = (const float*)d_in[15];

    const int B = 8, H = 352, W = 1216;
    const int H2 = 176, W2 = 608, H4 = 88, W4 = 304, H8 = 44, W8 = 152;
    const size_t F   = (size_t)64 * H * W;
    const size_t H2s = (size_t)64 * H2 * W2;
    const size_t Qs  = (size_t)64 * H4 * W4;
    const size_t Es  = (size_t)64 * H8 * W8;

    const size_t needH = 4 * F * sizeof(f16) + 28672;
    const size_t needFull = 4 * F * sizeof(f16) + 65536;
    if (ws_size < needH) return;
    const bool FULL = (ws_size >= needFull);  // ws_size fixed -> deterministic

    f16* ws = (f16*)d_ws;
    f16* P0x = ws;            // full-res NHWC (xc, c), persists to final decoder
    f16* P0c = ws + F;
    f16* Ux  = ws + 2 * F;    // full-res ping
    f16* Uc  = ws + 3 * F;
    f16* D1x = ws + 2 * F;    // half-res set aliases region 2 (4*H2s == F)
    f16* D1c = D1x + H2s;
    f16* D2x = D1c + H2s;
    f16* D2c = D2x + H2s;
    f16* Q1x = ws + 3 * F;    // quarter + eighth alias region 3
    f16* Q1c = Q1x + Qs;
    f16* Q2x = Q1c + Qs;
    f16* Q2c = Q2x + Qs;
    f16* E1x = Q2c + Qs;
    f16* E1c = E1x + Es;
    f16* E2x = E1c + Es;
    f16* E2c = E2x + Es;

    char* tail = (char*)d_ws + 4 * F * sizeof(f16);
    float* WT = (float*)tail;
    f16* BF2 = (f16*)(tail + 2048);
    f16* BF3 = (f16*)(tail + 9216);
    f16* BF1 = (f16*)(tail + 16384);
    // DF placement: FULL -> dedicated tail; fallback -> region-3 slack.
    f16* DF4 = FULL ? (f16*)(tail + 17408) : (ws + 3 * F + 16777216);
    f16* DF5 = DF4 + 3584;
    f16* DF6 = DF5 + 3584;

    const float* s1 = WT + 200;
    const float* s2 = WT + 208;
    const float* s3 = WT + 216;
    const float* s4 = WT + 224;
    const float* s5 = WT + 232;
    const float* s6 = WT + 240;
    const float* s7 = WT + 248;
    const float* wp7 = WT + 256;

    prep_misc<<<10, 256, 0, stream>>>(w1, w2, w3, w4, w5, w6, w7, WT, BF2, BF3, BF1);
    if (FULL)
        pack_dec_frag<<<3, 256, 0, stream>>>(w4, w5, w6, DF4, DF5, DF6);

    auto nb = [](size_t n) { return (int)((n + 255) / 256); };
    // enc/l1 grids: x = ceil(tilesW/4), y = ceil(H/CH), CH % 5 == 0, z = B.
    const dim3 geF(19, 18, 8);   // CH=20
    const dim3 geH(10, 18, 8);   // CH=10
    const dim3 geQ(5, 9, 8);     // CH=10
    const dim3 geE(3, 9, 8);     // CH=5
    // dec grids: CH % 6 == 0 (h0 even).
    const dim3 gdF(19, 30, 8);   // CH=12
    const dim3 gdH(10, 15, 8);   // CH=12
    const dim3 gdQ(5, 8, 8);     // CH=12

    // Encoder
    l1_mfma<<<geF, 256, 0, stream>>>(x0, c0, BF1, s1, b1, P0x, P0c, B, H, W, 20);
    enc5_mfma<<<geF, 256, 0, stream>>>(P0x, P0c, BF2, s2, b2, Ux, Uc, B, H, W, 20);
    enc5_mfma<<<geF, 256, 0, stream>>>(Ux, Uc, BF3, s3, b3, P0x, P0c, B, H, W, 20);
    if (!FULL)  // region-3 DF slack only safe now (Uc dead)
        pack_dec_frag<<<3, 256, 0, stream>>>(w4, w5, w6, DF4, DF5, DF6);
    pool_nhwc<<<nb((size_t)B * H2 * (W2 / 2)), 256, 0, stream>>>(P0x, P0c, D1x, D1c, B, H, W);
    enc5_mfma<<<geH, 256, 0, stream>>>(D1x, D1c, BF2, s2, b2, D2x, D2c, B, H2, W2, 10);
    enc5_mfma<<<geH, 256, 0, stream>>>(D2x, D2c, BF3, s3, b3, D1x, D1c, B, H2, W2, 10);
    pool_nhwc<<<nb((size_t)B * H4 * (W4 / 2)), 256, 0, stream>>>(D1x, D1c, Q1x, Q1c, B, H2, W2);
    enc5_mfma<<<geQ, 256, 0, stream>>>(Q1x, Q1c, BF2, s2, b2, Q2x, Q2c, B, H4, W4, 10);
    pool_nhwc<<<nb((size_t)B * H8 * (W8 / 2)), 256, 0, stream>>>(Q2x, Q2c, E1x, E1c, B, H4, W4);
    enc5_mfma<<<geE, 256, 0, stream>>>(E1x, E1c, BF2, s2, b2, E2x, E2c, B, H8, W8, 5);

    // Decoder: R = same-res source (per pack RB), S = half-res (parity-folded).
    dec3_mfma<false><<<gdQ, 256, 0, stream>>>(
        Q2x, Q2c, E2x, E2c, DF4, s4, b4, WT, WT, WT,
        Q1x, Q1c, (float*)nullptr, (float*)nullptr, B, H4, W4, 12);
    dec3_mfma<false><<<gdH, 256, 0, stream>>>(
        D1x, D1c, Q1x, Q1c, DF5, s5, b5, WT, WT, WT,
        D2x, D2c, (float*)nullptr, (float*)nullptr, B, H2, W2, 12);

    float* outx = (float*)d_out;
    float* outc = outx + (size_t)B * H * W;
    dec3_mfma<true><<<gdF, 256, 0, stream>>>(
        P0x, P0c, D2x, D2c, DF6, s6, b6, wp7, s7, b7,
        (f16*)nullptr, (f16*)nullptr, outx, outc, B, H, W, 12);
}

// Round 15
// 372.748 us; speedup vs baseline: 4.4610x; 4.4610x over previous
//
#include <hip/hip_runtime.h>
#include <cmath>

#define EPSV 1e-20f
#define MFMA16(A, B, C) __builtin_amdgcn_mfma_f32_16x16x32_f16(A, B, C, 0, 0, 0)

typedef _Float16 f16;
typedef _Float16 v8h __attribute__((ext_vector_type(8)));
typedef _Float16 h4 __attribute__((ext_vector_type(4)));
typedef float v4f __attribute__((ext_vector_type(4)));

__device__ __forceinline__ float softplusf(float x) {
    return fmaxf(x, 0.f) + log1pf(expf(-fabsf(x)));
}

__device__ __forceinline__ v8h v8h_zero() {
    v8h z = {0, 0, 0, 0, 0, 0, 0, 0};
    return z;
}

// lane l <- lane l+16. MUST be called with all 64 lanes active (ds_bpermute
// reads from inactive lanes are undefined) — never call inside divergence.
__device__ __forceinline__ v8h shfl_dn16(v8h v) {
    union { v8h h; int i[4]; } u, r;
    u.h = v;
#pragma unroll
    for (int k = 0; k < 4; ++k) r.i[k] = __shfl_down(u.i[k], 16, 64);
    return r.h;
}

// ---------------------------------------------------------------------------
// Weight prep, merged. WT floats: s_l @ [200+(l-1)*8], wp7 @ 256.
// BF2/BF3: enc 5x5 frags. BF1: l1 frag.
// ---------------------------------------------------------------------------
__global__ void prep_misc(const float* __restrict__ w1, const float* __restrict__ w2,
                          const float* __restrict__ w3, const float* __restrict__ w4,
                          const float* __restrict__ w5, const float* __restrict__ w6,
                          const float* __restrict__ w7, float* __restrict__ WT,
                          f16* __restrict__ BF2, f16* __restrict__ BF3,
                          f16* __restrict__ BF1) {
    int t = blockIdx.x;
    if (t < 7) {
        __shared__ float lds[1600];
        const float* srcs[7] = {w1, w2, w3, w4, w5, w6, w7};
        const int ns[7]    = {200, 1600, 1600, 1152, 1152, 1152, 8};
        const int pers[7]  = {25, 200, 200, 144, 144, 144, 8};
        const int couts[7] = {8, 8, 8, 8, 8, 8, 1};
        const float* src = srcs[t];
        int n = ns[t];
        for (int i = threadIdx.x; i < n; i += blockDim.x) {
            float v = softplusf(src[i]);
            lds[i] = v;
            if (t == 6) WT[256 + i] = v;  // wp7
        }
        __syncthreads();
        if ((int)threadIdx.x < couts[t]) {
            float s = 0.f;
            int per = pers[t];
            for (int i = 0; i < per; ++i) s += lds[threadIdx.x * per + i];
            WT[200 + t * 8 + threadIdx.x] = s;
        }
    } else if (t < 9) {
        // enc frags: g<5:(kh=g,kw=sub)  g==5:(kh=sub,kw=4)  g==6:(4,4) sub0
        const float* w = (t == 8) ? w3 : w2;
        f16* dst = (t == 8) ? BF3 : BF2;
        for (int i = threadIdx.x; i < 7 * 64 * 8; i += blockDim.x) {
            int g = i >> 9;
            int l = (i >> 3) & 63;
            int j = i & 7;
            int co = l & 15, sub = l >> 4;
            float v = 0.f;
            if (co < 8) {
                int kh = 0, kw = 0;
                bool valid = true;
                if (g < 5) { kh = g; kw = sub; }
                else if (g == 5) { kh = sub; kw = 4; }
                else { kh = 4; kw = 4; valid = (sub == 0); }
                if (valid) v = softplusf(w[((co * 8 + j) * 5 + kh) * 5 + kw]);
            }
            dst[i] = (f16)v;
        }
    } else {
        // l1 frag (CIN=1): j<=4:(kh=j,kw=sub)  j==5:(kh=sub,kw=4)  j==6:(4,4) sub0
        for (int i = threadIdx.x; i < 512; i += blockDim.x) {
            int l = i >> 3, j = i & 7;
            int co = l & 15, sub = l >> 4;
            float v = 0.f;
            if (co < 8) {
                if (j <= 4) v = softplusf(w1[co * 25 + j * 5 + sub]);
                else if (j == 5) v = softplusf(w1[co * 25 + sub * 5 + 4]);
                else if (j == 6 && sub == 0) v = softplusf(w1[co * 25 + 24]);
            }
            BF1[i] = (f16)v;
        }
    }
}

// Decoder 3x3 16ci weight frags with S parity folding. kw = sub (sub 3 zero).
//  g0-2: R block kh=g ; g3 = S kh0 ; g4 = S kh1+kh2 ; g5 = S kh0+kh1 ; g6 = S kh2
__global__ void pack_dec_frag(const float* __restrict__ w4, const float* __restrict__ w5,
                              const float* __restrict__ w6,
                              f16* __restrict__ dst4, f16* __restrict__ dst5,
                              f16* __restrict__ dst6) {
    const float* ww[3] = {w4, w5, w6};
    f16* dd[3] = {dst4, dst5, dst6};
    const int RBt[3] = {0, 0, 1};
    const float* w = ww[blockIdx.x];
    f16* dst = dd[blockIdx.x];
    const int rb = RBt[blockIdx.x], sbk = 1 - rb;
    for (int i = threadIdx.x; i < 7 * 64 * 8; i += blockDim.x) {
        int g = i >> 9;
        int l = (i >> 3) & 63;
        int j = i & 7;
        int co = l & 15, sub = l >> 4;
        float v = 0.f;
        if (co < 8 && sub < 3) {
            int kw = sub;
            auto W_ = [&](int blk, int kh) {
                return softplusf(w[((co * 16 + blk * 8 + j) * 3 + kh) * 3 + kw]);
            };
            if (g < 3) v = W_(rb, g);
            else if (g == 3) v = W_(sbk, 0);
            else if (g == 4) v = W_(sbk, 1) + W_(sbk, 2);
            else if (g == 5) v = W_(sbk, 0) + W_(sbk, 1);
            else v = W_(sbk, 2);
        }
        dst[i] = (f16)v;
    }
}

// ---------------------------------------------------------------------------
// Layer 1 via MFMA (CIN=1): fp32 planar (x,c) -> f16 NHWC (xc, c).
// ---------------------------------------------------------------------------
__global__ void __launch_bounds__(256) l1_mfma(
    const float* __restrict__ x0, const float* __restrict__ c0,
    const f16* __restrict__ afrag, const float* __restrict__ ssum,
    const float* __restrict__ bias,
    f16* __restrict__ xcout, f16* __restrict__ cout,
    int B, int H, int W, int CH) {
    const int lane = threadIdx.x & 63;
    const int wid = threadIdx.x >> 6;
    const int m = lane & 15, sub = lane >> 4;
    const int tilesW = (W + 15) >> 4;
    const int tw = blockIdx.x * 4 + wid;
    if (tw >= tilesW) return;
    const int w0 = tw << 4;
    const int b = blockIdx.z;
    const int h0 = blockIdx.y * CH;
    if (h0 >= H) return;

    v8h af = *(const v8h*)(afrag + lane * 8);

    float4 ssv = {1.f, 1.f, 1.f, 1.f}, bbv = {0.f, 0.f, 0.f, 0.f};
    if (sub < 2) {
        ssv = *(const float4*)(ssum + sub * 4);
        bbv = *(const float4*)(bias + sub * 4);
    }
    float rssv[4];
#pragma unroll
    for (int j = 0; j < 4; ++j) rssv[j] = __builtin_amdgcn_rcpf(((const float*)&ssv)[j]);

    const int HW = H * W;
    const float* cb = c0 + (size_t)b * HW;
    const float* xb = x0 + (size_t)b * HW;

    const unsigned W8u = (unsigned)W * 8;
    const unsigned bb8 = (unsigned)(b * H) * W8u;
    unsigned sbase = bb8 + (unsigned)h0 * W8u + (unsigned)(w0 + m) * 8 + sub * 4;

    auto epi = [&](const v4f& accd, const v4f& accn) {
        h4 xo8, c8;
#pragma unroll
        for (int j = 0; j < 4; ++j) {
            float d = accd[j];
            float cc = d * rssv[j];
            float x = accn[j] * __builtin_amdgcn_rcpf(d + EPSV) + ((const float*)&bbv)[j];
            c8[j] = (f16)cc;
            xo8[j] = (f16)(x * cc);
        }
        *(h4*)(cout + sbase) = c8;
        *(h4*)(xcout + sbase) = xo8;
    };

    const int colr = w0 + m + sub - 2;
    const int cole = w0 + m + 2;

    const bool fast = (w0 >= 2) && (w0 + 17 < W) && (h0 >= 2) && (h0 + CH + 2 <= H);
    if (fast) {
        const float* crow = cb + (size_t)(h0 - 2) * W + colr;
        const float* xrow = xb + (size_t)(h0 - 2) * W + colr;
        f16 rc[5], rx[5];
#pragma unroll
        for (int t = 0; t < 4; ++t) {
            float cv = *crow, xv = *xrow;
            crow += W; xrow += W;
            rc[t] = (f16)cv;
            rx[t] = (f16)(xv * cv);
        }
        rc[4] = (f16)0; rx[4] = (f16)0;
        const float* c5p = cb + (size_t)(h0 + sub - 2) * W + cole;
        const float* x5p = xb + (size_t)(h0 + sub - 2) * W + cole;
        const float* c6p = cb + (size_t)(h0 + 2) * W + cole;
        const float* x6p = xb + (size_t)(h0 + 2) * W + cole;
        const bool st = (sub < 2);
        for (int hh = 0; hh < CH; hh += 5) {
#pragma unroll
            for (int p = 0; p < 5; ++p) {
                float cv = *crow, xv = *xrow;
                crow += W; xrow += W;
                rc[(p + 4) % 5] = (f16)cv;
                rx[(p + 4) % 5] = (f16)(xv * cv);
                float c5 = *c5p, x5 = *x5p;
                c5p += W; x5p += W;
                float c6 = *c6p, x6 = *x6p;
                c6p += W; x6p += W;
                f16 e5c = (f16)c5, e5x = (f16)(x5 * c5);
                f16 e6c = (f16)c6, e6x = (f16)(x6 * c6);
                v8h bc = {rc[p % 5], rc[(p + 1) % 5], rc[(p + 2) % 5],
                          rc[(p + 3) % 5], rc[(p + 4) % 5], e5c, e6c, (f16)0};
                v8h bx = {rx[p % 5], rx[(p + 1) % 5], rx[(p + 2) % 5],
                          rx[(p + 3) % 5], rx[(p + 4) % 5], e5x, e6x, (f16)0};
                v4f z = {0.f, 0.f, 0.f, 0.f};
                v4f accd = MFMA16(af, bc, z);
                v4f accn = MFMA16(af, bx, z);
                if (st) epi(accd, accn);
                sbase += W8u;
            }
        }
    } else {
        const bool okr = (colr >= 0) && (colr < W);
        const bool oke = (cole < W);
        const int colrc = min(max(colr, 0), W - 1);
        const int colec = min(cole, W - 1);
        const bool st = (sub < 2) && (w0 + m < W);
        for (int hh = 0; hh < CH; ++hh) {
            const int h = h0 + hh;
            if (h >= H) break;
            f16 vc[8], vx[8];
#pragma unroll
            for (int j = 0; j < 5; ++j) {
                int r = h + j - 2;
                bool ok = okr && (r >= 0) && (r < H);
                int rcl = min(max(r, 0), H - 1);
                float cv = cb[(size_t)rcl * W + colrc];
                float xv = xb[(size_t)rcl * W + colrc];
                vc[j] = ok ? (f16)cv : (f16)0;
                vx[j] = ok ? (f16)(xv * cv) : (f16)0;
            }
            {
                int r = h + sub - 2;
                bool ok = oke && (r >= 0) && (r < H);
                int rcl = min(max(r, 0), H - 1);
                float cv = cb[(size_t)rcl * W + colec];
                float xv = xb[(size_t)rcl * W + colec];
                vc[5] = ok ? (f16)cv : (f16)0;
                vx[5] = ok ? (f16)(xv * cv) : (f16)0;
            }
            {
                int r = h + 2;
                bool ok = oke && (r < H);
                int rcl = min(r, H - 1);
                float cv = cb[(size_t)rcl * W + colec];
                float xv = xb[(size_t)rcl * W + colec];
                vc[6] = ok ? (f16)cv : (f16)0;
                vx[6] = ok ? (f16)(xv * cv) : (f16)0;
            }
            vc[7] = (f16)0; vx[7] = (f16)0;
            v8h bc = {vc[0], vc[1], vc[2], vc[3], vc[4], vc[5], vc[6], vc[7]};
            v8h bx = {vx[0], vx[1], vx[2], vx[3], vx[4], vx[5], vx[6], vx[7]};
            v4f z = {0.f, 0.f, 0.f, 0.f};
            v4f accd = MFMA16(af, bc, z);
            v4f accn = MFMA16(af, bx, z);
            if (st) epi(accd, accn);
            sbase += W8u;
        }
    }
}

// ---------------------------------------------------------------------------
// Pool-gather NHWC, 2 output pixels per thread.
// ---------------------------------------------------------------------------
__global__ void __launch_bounds__(256) pool_nhwc(
    const f16* __restrict__ xc, const f16* __restrict__ c,
    f16* __restrict__ xo, f16* __restrict__ co_,
    int B, int H, int W) {
    int H2 = H >> 1, W2 = W >> 1, Wh = W2 >> 1;
    int idx = blockIdx.x * 256 + threadIdx.x;
    int total = B * H2 * Wh;
    if (idx >= total) return;
    int wo = (idx % Wh) * 2;
    int ho = (idx / Wh) % H2;
    int b = idx / (Wh * H2);
    unsigned base = (unsigned)(((b * H + 2 * ho) * W + 2 * wo) * 8);
    unsigned rb = (unsigned)(W * 8);
    v8h c0r[4], c1r[4], x0r[4], x1r[4];
#pragma unroll
    for (int i = 0; i < 4; ++i) {
        c0r[i] = *(const v8h*)(c + base + 8 * i);
        c1r[i] = *(const v8h*)(c + base + rb + 8 * i);
        x0r[i] = *(const v8h*)(xc + base + 8 * i);
        x1r[i] = *(const v8h*)(xc + base + rb + 8 * i);
    }
    unsigned oa = (unsigned)(((b * H2 + ho) * W2 + wo) * 8);
#pragma unroll
    for (int p = 0; p < 2; ++p) {
        v8h xr, cr;
#pragma unroll
        for (int e = 0; e < 8; ++e) {
            float b0 = (float)c0r[2 * p][e], b1 = (float)c0r[2 * p + 1][e];
            float b2 = (float)c1r[2 * p][e], b3 = (float)c1r[2 * p + 1][e];
            float cb = b0;
            float xv = (float)x0r[2 * p][e];
            if (b1 > cb) { cb = b1; xv = (float)x0r[2 * p + 1][e]; }
            if (b2 > cb) { cb = b2; xv = (float)x1r[2 * p][e]; }
            if (b3 > cb) { cb = b3; xv = (float)x1r[2 * p + 1][e]; }
            xr[e] = (f16)(xv * 0.25f);
            cr[e] = (f16)(cb * 0.25f);
        }
        *(v8h*)(xo + oa + p * 8) = xr;
        *(v8h*)(co_ + oa + p * 8) = cr;
    }
}

// ---------------------------------------------------------------------------
// Encoder nconv via MFMA. Fast path: 5-ring rotation + E5 cross-lane rotation
// (shfl executed with full exec, then per-lane select). 4 loads/row.
// NOTE: no __launch_bounds__ min-wave arg — forcing 8 waves/EU made the
// allocator spill to scratch (VGPR 32, 1.9 GB scratch traffic, 8x slower).
// CH multiple of 5.
// ---------------------------------------------------------------------------
__global__ void __launch_bounds__(256) enc5_mfma(
    const f16* __restrict__ xcin, const f16* __restrict__ cin,
    const f16* __restrict__ bfrag, const float* __restrict__ ssum,
    const float* __restrict__ bias,
    f16* __restrict__ xcout, f16* __restrict__ cout,
    int B, int H, int W, int CH) {
    const int lane = threadIdx.x & 63;
    const int wid = threadIdx.x >> 6;
    const int m = lane & 15, sub = lane >> 4;
    const int tilesW = (W + 15) >> 4;
    const int tw = blockIdx.x * 4 + wid;
    if (tw >= tilesW) return;
    const int w0 = tw << 4;
    const int b = blockIdx.z;
    const int h0 = blockIdx.y * CH;
    if (h0 >= H) return;

    v8h bf[7];
#pragma unroll
    for (int g = 0; g < 7; ++g)
        bf[g] = *(const v8h*)(bfrag + ((g << 6) + lane) * 8);

    float4 ssv = {1.f, 1.f, 1.f, 1.f}, bbv = {0.f, 0.f, 0.f, 0.f};
    if (sub < 2) {
        ssv = *(const float4*)(ssum + sub * 4);
        bbv = *(const float4*)(bias + sub * 4);
    }
    float rssv[4];
#pragma unroll
    for (int j = 0; j < 4; ++j) rssv[j] = __builtin_amdgcn_rcpf(((const float*)&ssv)[j]);

    const unsigned W8u = (unsigned)W * 8;
    const unsigned bb8 = (unsigned)(b * H) * W8u;
    unsigned sbase = bb8 + (unsigned)h0 * W8u + (unsigned)(w0 + m) * 8 + sub * 4;

    auto epi = [&](const v4f& accd, const v4f& accn) {
        h4 xo8, c8;
#pragma unroll
        for (int j = 0; j < 4; ++j) {
            float d = accd[j];
            float cc = d * rssv[j];
            float x = accn[j] * __builtin_amdgcn_rcpf(d + EPSV) + ((const float*)&bbv)[j];
            c8[j] = (f16)cc;
            xo8[j] = (f16)(x * cc);
        }
        *(h4*)(cout + sbase) = c8;
        *(h4*)(xcout + sbase) = xo8;
    };

    const bool fast = (w0 >= 2) && (w0 + 17 < W) && (h0 >= 2) && (h0 + CH + 2 <= H);
    if (fast) {
        v8h Rc[5], Rx[5];
        unsigned aRot = bb8 + (unsigned)(h0 - 2) * W8u + (unsigned)(w0 + m + sub - 2) * 8;
#pragma unroll
        for (int t = 0; t < 4; ++t) {
            Rc[t] = *(const v8h*)(cin + aRot);
            Rx[t] = *(const v8h*)(xcin + aRot);
            aRot += W8u;
        }
        // E5 warm-up: row h0+sub-2, col w0+m+2
        unsigned aE5w = bb8 + (unsigned)(h0 + sub - 2) * W8u + (unsigned)(w0 + m + 2) * 8;
        v8h E5c = *(const v8h*)(cin + aE5w);
        v8h E5x = *(const v8h*)(xcin + aE5w);
        unsigned aE6 = bb8 + (unsigned)(h0 + 2) * W8u + (unsigned)(w0 + m + 2) * 8;
        const bool st = (sub < 2);
        for (int hh = 0; hh < CH; hh += 5) {
#pragma unroll
            for (int p = 0; p < 5; ++p) {
                Rc[(p + 4) % 5] = *(const v8h*)(cin + aRot);
                Rx[(p + 4) % 5] = *(const v8h*)(xcin + aRot);
                aRot += W8u;
                v8h e6c = *(const v8h*)(cin + aE6);
                v8h e6x = *(const v8h*)(xcin + aE6);
                aE6 += W8u;

                v4f accd = {0.f, 0.f, 0.f, 0.f}, accn = {0.f, 0.f, 0.f, 0.f};
#pragma unroll
                for (int g = 0; g < 5; ++g) {
                    accd = MFMA16(bf[g], Rc[(p + g) % 5], accd);
                    accn = MFMA16(bf[g], Rx[(p + g) % 5], accn);
                }
                accd = MFMA16(bf[5], E5c, accd);
                accn = MFMA16(bf[5], E5x, accn);
                accd = MFMA16(bf[6], e6c, accd);
                accn = MFMA16(bf[6], e6x, accn);

                // rotate E5 for next row: shfl with FULL exec, then select.
                v8h rotc = shfl_dn16(E5c);
                v8h rotx = shfl_dn16(E5x);
                E5c = (sub < 3) ? rotc : e6c;
                E5x = (sub < 3) ? rotx : e6x;

                if (st) epi(accd, accn);
                sbase += W8u;
            }
        }
    } else {
        const int cwr = w0 + m + sub - 2;
        const bool okc_r = (cwr >= 0) && (cwr < W);
        const unsigned a_rot = (unsigned)min(max(cwr, 0), W - 1) * 8;
        const int cwe = w0 + m + 2;
        const bool okc_e = cwe < W;
        const unsigned a_e = (unsigned)min(cwe, W - 1) * 8;
        const bool doStore = (sub < 2) && (w0 + m < W);

        v8h Rc[5], Rx[5];
#pragma unroll
        for (int t = 0; t < 4; ++t) {
            int r = h0 - 2 + t;
            bool ok = (r >= 0) && (r < H) && okc_r;
            unsigned a = bb8 + (unsigned)min(max(r, 0), H - 1) * W8u + a_rot;
            v8h pc = *(const v8h*)(cin + a);
            v8h px = *(const v8h*)(xcin + a);
            Rc[t] = ok ? pc : v8h_zero();
            Rx[t] = ok ? px : v8h_zero();
        }
        Rc[4] = v8h_zero();
        Rx[4] = v8h_zero();

        for (int hh = 0; hh < CH; hh += 5) {
#pragma unroll
            for (int p = 0; p < 5; ++p) {
                const int h = h0 + hh + p;
                {
                    int r = h + 2;
                    bool ok = (r < H) && okc_r;
                    unsigned a = bb8 + (unsigned)min(r, H - 1) * W8u + a_rot;
                    v8h pc = *(const v8h*)(cin + a);
                    v8h px = *(const v8h*)(xcin + a);
                    Rc[(p + 4) % 5] = ok ? pc : v8h_zero();
                    Rx[(p + 4) % 5] = ok ? px : v8h_zero();
                }
                v8h e5c, e5x;
                {
                    int r = h + sub - 2;
                    bool ok = (r >= 0) && (r < H) && okc_e;
                    unsigned a = bb8 + (unsigned)min(max(r, 0), H - 1) * W8u + a_e;
                    v8h pc = *(const v8h*)(cin + a);
                    v8h px = *(const v8h*)(xcin + a);
                    e5c = ok ? pc : v8h_zero();
                    e5x = ok ? px : v8h_zero();
                }
                v8h e6c, e6x;
                {
                    int r = h + 2;
                    bool ok = (r < H) && okc_e;
                    unsigned a = bb8 + (unsigned)min(r, H - 1) * W8u + a_e;
                    v8h pc = *(const v8h*)(cin + a);
                    v8h px = *(const v8h*)(xcin + a);
                    e6c = ok ? pc : v8h_zero();
                    e6x = ok ? px : v8h_zero();
                }

                v4f accd = {0.f, 0.f, 0.f, 0.f}, accn = {0.f, 0.f, 0.f, 0.f};
#pragma unroll
                for (int g = 0; g < 5; ++g) {
                    accd = MFMA16(bf[g], Rc[(p + g) % 5], accd);
                    accn = MFMA16(bf[g], Rx[(p + g) % 5], accn);
                }
                accd = MFMA16(bf[5], e5c, accd);
                accn = MFMA16(bf[5], e5x, accn);
                accd = MFMA16(bf[6], e6c, accd);
                accn = MFMA16(bf[6], e6x, accn);

                if (doStore && h < H) epi(accd, accn);
                sbase += W8u;
            }
        }
    }
}

// ---------------------------------------------------------------------------
// Decoder nconv via MFMA (round-10 verified): R = same-res source (bf 0-2,
// rotating ring 3), S = half-res source with parity-folded weights (bf 3-6).
// CH multiple of 6, h0 even. FUSE7: fused final 1x1 nconv, fp32 1-ch outputs.
// ---------------------------------------------------------------------------
template <bool FUSE7>
__global__ void __launch_bounds__(256) dec3_mfma(
    const f16* __restrict__ xcR, const f16* __restrict__ cR,
    const f16* __restrict__ xcS, const f16* __restrict__ cS,
    const f16* __restrict__ bfrag,
    const float* __restrict__ ssum, const float* __restrict__ bias,
    const float* __restrict__ wp7, const float* __restrict__ s7p,
    const float* __restrict__ b7p,
    f16* __restrict__ xcout, f16* __restrict__ ccout,
    float* __restrict__ xoutf, float* __restrict__ coutf,
    int B, int H, int W, int CH) {
    const int lane = threadIdx.x & 63;
    const int wid = threadIdx.x >> 6;
    const int m = lane & 15, sub = lane >> 4;
    const int tilesW = W >> 4;
    const int tw = blockIdx.x * 4 + wid;
    if (tw >= tilesW) return;
    const int w0 = tw << 4;
    const int b = blockIdx.z;
    const int h0 = blockIdx.y * CH;
    if (h0 >= H) return;

    v8h bf[7];
#pragma unroll
    for (int g = 0; g < 7; ++g)
        bf[g] = *(const v8h*)(bfrag + ((g << 6) + lane) * 8);

    const int cw = w0 + m + sub - 1;
    const bool okc = (cw >= 0) && (cw < W);
    const int cwc = min(max(cw, 0), W - 1);
    const unsigned aRc = (unsigned)cwc * 8;
    const unsigned aSc = (unsigned)(cwc >> 1) * 8;

    const int Hs = H >> 1, Ws = W >> 1;
    const unsigned WR8 = (unsigned)W * 8;
    const unsigned WS8 = (unsigned)Ws * 8;
    const unsigned bbR = (unsigned)(b * H) * WR8;
    const unsigned bbS = (unsigned)(b * Hs) * WS8;

    float4 ssv = {1.f, 1.f, 1.f, 1.f}, bbv = {0.f, 0.f, 0.f, 0.f};
    float4 w7v = {0.f, 0.f, 0.f, 0.f};
    if (sub < 2) {
        ssv = *(const float4*)(ssum + sub * 4);
        bbv = *(const float4*)(bias + sub * 4);
        if (FUSE7) w7v = *(const float4*)(wp7 + sub * 4);
    }
    float rssv[4];
#pragma unroll
    for (int j = 0; j < 4; ++j) rssv[j] = __builtin_amdgcn_rcpf(((const float*)&ssv)[j]);
    float rs7 = 0.f, b7v = 0.f;
    if (FUSE7) { rs7 = __builtin_amdgcn_rcpf(s7p[0]); b7v = b7p[0]; }

    unsigned sbase = bbR + (unsigned)h0 * WR8 + (unsigned)(w0 + m) * 8 + sub * 4;
    unsigned opix = (unsigned)(b * H + h0) * (unsigned)W + (unsigned)w0;

    auto epi = [&](const v4f& accd, const v4f& accn) {
        if constexpr (FUSE7) {
            float td = 0.f, tn = 0.f;
#pragma unroll
            for (int j = 0; j < 4; ++j) {
                float d = accd[j];  // exactly 0 for co>=8 (weights zeroed)
                float cc = d * rssv[j];
                float o = accn[j] * __builtin_amdgcn_rcpf(d + EPSV) + ((const float*)&bbv)[j];
                td = fmaf(((const float*)&w7v)[j], cc, td);
                tn = fmaf(((const float*)&w7v)[j], o * cc, tn);
            }
            td += __shfl_xor(td, 16);
            tn += __shfl_xor(tn, 16);
            td += __shfl_xor(td, 32);
            tn += __shfl_xor(tn, 32);
            if (sub == 0) {
                xoutf[opix + m] = tn * __builtin_amdgcn_rcpf(td + EPSV) + b7v;
            } else if (sub == 1) {
                coutf[opix + m] = td * rs7;
            }
        } else {
            if (sub < 2) {
                h4 xo8, c8;
#pragma unroll
                for (int j = 0; j < 4; ++j) {
                    float d = accd[j];
                    float cc = d * rssv[j];
                    float x = accn[j] * __builtin_amdgcn_rcpf(d + EPSV) + ((const float*)&bbv)[j];
                    c8[j] = (f16)cc;
                    xo8[j] = (f16)(x * cc);
                }
                *(h4*)(ccout + sbase) = c8;
                *(h4*)(xcout + sbase) = xo8;
            }
        }
    };

    const bool fast = (w0 >= 1) && (w0 + 17 < W) && (h0 >= 2) && (h0 + CH + 1 <= H);
    if (fast) {
        v8h Rc_[3], Rx_[3], Sc_[3], Sx_[3];
        unsigned ar = bbR + (unsigned)(h0 - 1) * WR8 + aRc;
        Rc_[2] = *(const v8h*)(cR + ar); Rx_[2] = *(const v8h*)(xcR + ar); ar += WR8;
        Rc_[0] = *(const v8h*)(cR + ar); Rx_[0] = *(const v8h*)(xcR + ar); ar += WR8;
        const int k0 = h0 >> 1;
        unsigned as_ = bbS + (unsigned)(k0 - 1) * WS8 + aSc;
        Sc_[2] = *(const v8h*)(cS + as_); Sx_[2] = *(const v8h*)(xcS + as_); as_ += WS8;
        Sc_[0] = *(const v8h*)(cS + as_); Sx_[0] = *(const v8h*)(xcS + as_); as_ += WS8;

        for (int hh = 0; hh < CH; hh += 6) {
#pragma unroll
            for (int p = 0; p < 6; ++p) {
                const int j = p >> 1;
                Rc_[(p + 1) % 3] = *(const v8h*)(cR + ar);
                Rx_[(p + 1) % 3] = *(const v8h*)(xcR + ar);
                ar += WR8;
                if ((p & 1) == 0) {  // prefetch S row k+1
                    Sc_[(j + 1) % 3] = *(const v8h*)(cS + as_);
                    Sx_[(j + 1) % 3] = *(const v8h*)(xcS + as_);
                    as_ += WS8;
                }
                v4f accd = {0.f, 0.f, 0.f, 0.f}, accn = {0.f, 0.f, 0.f, 0.f};
#pragma unroll
                for (int g = 0; g < 3; ++g) {
                    accd = MFMA16(bf[g], Rc_[(p + g + 2) % 3], accd);
                    accn = MFMA16(bf[g], Rx_[(p + g + 2) % 3], accn);
                }
                if ((p & 1) == 0) {  // even h: W0 on S[k-1], W12 on S[k]
                    accd = MFMA16(bf[3], Sc_[(j + 2) % 3], accd);
                    accn = MFMA16(bf[3], Sx_[(j + 2) % 3], accn);
                    accd = MFMA16(bf[4], Sc_[j % 3], accd);
                    accn = MFMA16(bf[4], Sx_[j % 3], accn);
                } else {             // odd h: W01 on S[k], W2 on S[k+1]
                    accd = MFMA16(bf[5], Sc_[j % 3], accd);
                    accn = MFMA16(bf[5], Sx_[j % 3], accn);
                    accd = MFMA16(bf[6], Sc_[(j + 1) % 3], accd);
                    accn = MFMA16(bf[6], Sx_[(j + 1) % 3], accn);
                }
                epi(accd, accn);
                sbase += WR8;
                opix += W;
            }
        }
    } else {
        for (int hh = 0; hh < CH; ++hh) {
            const int h = h0 + hh;
            if (h >= H) break;
            const int k = h >> 1;
            const bool ev = (h & 1) == 0;
            v4f accd = {0.f, 0.f, 0.f, 0.f}, accn = {0.f, 0.f, 0.f, 0.f};
#pragma unroll
            for (int g = 0; g < 3; ++g) {
                int r = h + g - 1;
                bool ok = okc && (r >= 0) && (r < H);
                unsigned a = bbR + (unsigned)min(max(r, 0), H - 1) * WR8 + aRc;
                v8h pc = *(const v8h*)(cR + a);
                v8h px = *(const v8h*)(xcR + a);
                if (!ok) { pc = v8h_zero(); px = v8h_zero(); }
                accd = MFMA16(bf[g], pc, accd);
                accn = MFMA16(bf[g], px, accn);
            }
            {
                int rs = ev ? (k - 1) : k;
                bool ok = okc && (!ev || (h >= 1));
                unsigned a = bbS + (unsigned)min(max(rs, 0), Hs - 1) * WS8 + aSc;
                v8h pc = *(const v8h*)(cS + a);
                v8h px = *(const v8h*)(xcS + a);
                if (!ok) { pc = v8h_zero(); px = v8h_zero(); }
                v8h wA = ev ? bf[3] : bf[5];
                accd = MFMA16(wA, pc, accd);
                accn = MFMA16(wA, px, accn);
            }
            {
                int rs = ev ? k : (k + 1);
                bool ok = okc && (ev || (h + 1 < H));
                unsigned a = bbS + (unsigned)min(max(rs, 0), Hs - 1) * WS8 + aSc;
                v8h pc = *(const v8h*)(cS + a);
                v8h px = *(const v8h*)(xcS + a);
                if (!ok) { pc = v8h_zero(); px = v8h_zero(); }
                v8h wB = ev ? bf[4] : bf[6];
                accd = MFMA16(wB, pc, accd);
                accn = MFMA16(wB, px, accn);
            }
            epi(accd, accn);
            sbase += WR8;
            opix += W;
        }
    }
}

// ---------------------------------------------------------------------------
extern "C" void kernel_launch(void* const* d_in, const int* in_sizes, int n_in,
                              void* d_out, int out_size, void* d_ws, size_t ws_size,
                              hipStream_t stream) {
    const float* x0 = (const float*)d_in[0];
    const float* c0 = (const float*)d_in[1];
    const float* w1 = (const float*)d_in[2];
    const float* b1 = (const float*)d_in[3];
    const float* w2 = (const float*)d_in[4];
    const float* b2 = (const float*)d_in[5];
    const float* w3 = (const float*)d_in[6];
    const float* b3 = (const float*)d_in[7];
    const float* w4 = (const float*)d_in[8];
    const float* b4 = (const float*)d_in[9];
    const float* w5 = (const float*)d_in[10];
    const float* b5 = (const float*)d_in[11];
    const float* w6 = (const float*)d_in[12];
    const float* b6 = (const float*)d_in[13];
    const float* w7 = (const float*)d_in[14];
    const float* b7 = (const float*)d_in[15];

    const int B = 8, H = 352, W = 1216;
    const int H2 = 176, W2 = 608, H4 = 88, W4 = 304, H8 = 44, W8 = 152;
    const size_t F   = (size_t)64 * H * W;
    const size_t H2s = (size_t)64 * H2 * W2;
    const size_t Qs  = (size_t)64 * H4 * W4;
    const size_t Es  = (size_t)64 * H8 * W8;

    const size_t needH = 4 * F * sizeof(f16) + 28672;
    const size_t needFull = 4 * F * sizeof(f16) + 65536;
    if (ws_size < needH) return;
    const bool FULL = (ws_size >= needFull);  // ws_size fixed -> deterministic

    f16* ws = (f16*)d_ws;
    f16* P0x = ws;            // full-res NHWC (xc, c), persists to final decoder
    f16* P0c = ws + F;
    f16* Ux  = ws + 2 * F;    // full-res ping
    f16* Uc  = ws + 3 * F;
    f16* D1x = ws + 2 * F;    // half-res set aliases region 2 (4*H2s == F)
    f16* D1c = D1x + H2s;
    f16* D2x = D1c + H2s;
    f16* D2c = D2x + H2s;
    f16* Q1x = ws + 3 * F;    // quarter + eighth alias region 3
    f16* Q1c = Q1x + Qs;
    f16* Q2x = Q1c + Qs;
    f16* Q2c = Q2x + Qs;
    f16* E1x = Q2c + Qs;
    f16* E1c = E1x + Es;
    f16* E2x = E1c + Es;
    f16* E2c = E2x + Es;

    char* tail = (char*)d_ws + 4 * F * sizeof(f16);
    float* WT = (float*)tail;
    f16* BF2 = (f16*)(tail + 2048);
    f16* BF3 = (f16*)(tail + 9216);
    f16* BF1 = (f16*)(tail + 16384);
    // DF placement: FULL -> dedicated tail; fallback -> region-3 slack.
    f16* DF4 = FULL ? (f16*)(tail + 17408) : (ws + 3 * F + 16777216);
    f16* DF5 = DF4 + 3584;
    f16* DF6 = DF5 + 3584;

    const float* s1 = WT + 200;
    const float* s2 = WT + 208;
    const float* s3 = WT + 216;
    const float* s4 = WT + 224;
    const float* s5 = WT + 232;
    const float* s6 = WT + 240;
    const float* s7 = WT + 248;
    const float* wp7 = WT + 256;

    prep_misc<<<10, 256, 0, stream>>>(w1, w2, w3, w4, w5, w6, w7, WT, BF2, BF3, BF1);
    if (FULL)
        pack_dec_frag<<<3, 256, 0, stream>>>(w4, w5, w6, DF4, DF5, DF6);

    auto nb = [](size_t n) { return (int)((n + 255) / 256); };
    // enc/l1 grids: x = ceil(tilesW/4), y = ceil(H/CH), CH % 5 == 0, z = B.
    const dim3 geF(19, 18, 8);   // CH=20
    const dim3 geH(10, 18, 8);   // CH=10
    const dim3 geQ(5, 9, 8);     // CH=10
    const dim3 geE(3, 9, 8);     // CH=5
    // dec grids: CH % 6 == 0 (h0 even).
    const dim3 gdF(19, 30, 8);   // CH=12
    const dim3 gdH(10, 15, 8);   // CH=12
    const dim3 gdQ(5, 8, 8);     // CH=12

    // Encoder
    l1_mfma<<<geF, 256, 0, stream>>>(x0, c0, BF1, s1, b1, P0x, P0c, B, H, W, 20);
    enc5_mfma<<<geF, 256, 0, stream>>>(P0x, P0c, BF2, s2, b2, Ux, Uc, B, H, W, 20);
    enc5_mfma<<<geF, 256, 0, stream>>>(Ux, Uc, BF3, s3, b3, P0x, P0c, B, H, W, 20);
    if (!FULL)  // region-3 DF slack only safe now (Uc dead)
        pack_dec_frag<<<3, 256, 0, stream>>>(w4, w5, w6, DF4, DF5, DF6);
    pool_nhwc<<<nb((size_t)B * H2 * (W2 / 2)), 256, 0, stream>>>(P0x, P0c, D1x, D1c, B, H, W);
    enc5_mfma<<<geH, 256, 0, stream>>>(D1x, D1c, BF2, s2, b2, D2x, D2c, B, H2, W2, 10);
    enc5_mfma<<<geH, 256, 0, stream>>>(D2x, D2c, BF3, s3, b3, D1x, D1c, B, H2, W2, 10);
    pool_nhwc<<<nb((size_t)B * H4 * (W4 / 2)), 256, 0, stream>>>(D1x, D1c, Q1x, Q1c, B, H2, W2);
    enc5_mfma<<<geQ, 256, 0, stream>>>(Q1x, Q1c, BF2, s2, b2, Q2x, Q2c, B, H4, W4, 10);
    pool_nhwc<<<nb((size_t)B * H8 * (W8 / 2)), 256, 0, stream>>>(Q2x, Q2c, E1x, E1c, B, H4, W4);
    enc5_mfma<<<geE, 256, 0, stream>>>(E1x, E1c, BF2, s2, b2, E2x, E2c, B, H8, W8, 5);

    // Decoder: R = same-res source (per pack RB), S = half-res (parity-folded).
    dec3_mfma<false><<<gdQ, 256, 0, stream>>>(
        Q2x, Q2c, E2x, E2c, DF4, s4, b4, WT, WT, WT,
        Q1x, Q1c, (float*)nullptr, (float*)nullptr, B, H4, W4, 12);
    dec3_mfma<false><<<gdH, 256, 0, stream>>>(
        D1x, D1c, Q1x, Q1c, DF5, s5, b5, WT, WT, WT,
        D2x, D2c, (float*)nullptr, (float*)nullptr, B, H2, W2, 12);

    float* outx = (float*)d_out;
    float* outc = outx + (size_t)B * H * W;
    dec3_mfma<true><<<gdF, 256, 0, stream>>>(
        P0x, P0c, D2x, D2c, DF6, s6, b6, wp7, s7, b7,
        (f16*)nullptr, (f16*)nullptr, outx, outc, B, H, W, 12);
}

// Round 16
// 368.983 us; speedup vs baseline: 4.5065x; 1.0102x over previous
//
#include <hip/hip_runtime.h>
#include <cmath>

#define EPSV 1e-20f
#define MFMA16(A, B, C) __builtin_amdgcn_mfma_f32_16x16x32_f16(A, B, C, 0, 0, 0)

typedef _Float16 f16;
typedef _Float16 v8h __attribute__((ext_vector_type(8)));
typedef _Float16 h4 __attribute__((ext_vector_type(4)));
typedef float v4f __attribute__((ext_vector_type(4)));

__device__ __forceinline__ float softplusf(float x) {
    return fmaxf(x, 0.f) + log1pf(expf(-fabsf(x)));
}

__device__ __forceinline__ v8h v8h_zero() {
    v8h z = {0, 0, 0, 0, 0, 0, 0, 0};
    return z;
}

// lane l <- lane l+16. MUST be called with all 64 lanes active (ds_bpermute
// reads from inactive lanes are undefined) — never call inside divergence.
__device__ __forceinline__ v8h shfl_dn16(v8h v) {
    union { v8h h; int i[4]; } u, r;
    u.h = v;
#pragma unroll
    for (int k = 0; k < 4; ++k) r.i[k] = __shfl_down(u.i[k], 16, 64);
    return r.h;
}

// ---------------------------------------------------------------------------
// Weight prep, merged. WT floats: s_l @ [200+(l-1)*8], wp7 @ 256.
// BF2/BF3: enc 5x5 frags. BF1: l1 frag.
// ---------------------------------------------------------------------------
__global__ void prep_misc(const float* __restrict__ w1, const float* __restrict__ w2,
                          const float* __restrict__ w3, const float* __restrict__ w4,
                          const float* __restrict__ w5, const float* __restrict__ w6,
                          const float* __restrict__ w7, float* __restrict__ WT,
                          f16* __restrict__ BF2, f16* __restrict__ BF3,
                          f16* __restrict__ BF1) {
    int t = blockIdx.x;
    if (t < 7) {
        __shared__ float lds[1600];
        const float* srcs[7] = {w1, w2, w3, w4, w5, w6, w7};
        const int ns[7]    = {200, 1600, 1600, 1152, 1152, 1152, 8};
        const int pers[7]  = {25, 200, 200, 144, 144, 144, 8};
        const int couts[7] = {8, 8, 8, 8, 8, 8, 1};
        const float* src = srcs[t];
        int n = ns[t];
        for (int i = threadIdx.x; i < n; i += blockDim.x) {
            float v = softplusf(src[i]);
            lds[i] = v;
            if (t == 6) WT[256 + i] = v;  // wp7
        }
        __syncthreads();
        if ((int)threadIdx.x < couts[t]) {
            float s = 0.f;
            int per = pers[t];
            for (int i = 0; i < per; ++i) s += lds[threadIdx.x * per + i];
            WT[200 + t * 8 + threadIdx.x] = s;
        }
    } else if (t < 9) {
        // enc frags: g<5:(kh=g,kw=sub)  g==5:(kh=sub,kw=4)  g==6:(4,4) sub0
        const float* w = (t == 8) ? w3 : w2;
        f16* dst = (t == 8) ? BF3 : BF2;
        for (int i = threadIdx.x; i < 7 * 64 * 8; i += blockDim.x) {
            int g = i >> 9;
            int l = (i >> 3) & 63;
            int j = i & 7;
            int co = l & 15, sub = l >> 4;
            float v = 0.f;
            if (co < 8) {
                int kh = 0, kw = 0;
                bool valid = true;
                if (g < 5) { kh = g; kw = sub; }
                else if (g == 5) { kh = sub; kw = 4; }
                else { kh = 4; kw = 4; valid = (sub == 0); }
                if (valid) v = softplusf(w[((co * 8 + j) * 5 + kh) * 5 + kw]);
            }
            dst[i] = (f16)v;
        }
    } else {
        // l1 frag (CIN=1): j<=4:(kh=j,kw=sub)  j==5:(kh=sub,kw=4)  j==6:(4,4) sub0
        for (int i = threadIdx.x; i < 512; i += blockDim.x) {
            int l = i >> 3, j = i & 7;
            int co = l & 15, sub = l >> 4;
            float v = 0.f;
            if (co < 8) {
                if (j <= 4) v = softplusf(w1[co * 25 + j * 5 + sub]);
                else if (j == 5) v = softplusf(w1[co * 25 + sub * 5 + 4]);
                else if (j == 6 && sub == 0) v = softplusf(w1[co * 25 + 24]);
            }
            BF1[i] = (f16)v;
        }
    }
}

// Decoder 3x3 16ci weight frags with S parity folding. kw = sub (sub 3 zero).
//  g0-2: R block kh=g ; g3 = S kh0 ; g4 = S kh1+kh2 ; g5 = S kh0+kh1 ; g6 = S kh2
__global__ void pack_dec_frag(const float* __restrict__ w4, const float* __restrict__ w5,
                              const float* __restrict__ w6,
                              f16* __restrict__ dst4, f16* __restrict__ dst5,
                              f16* __restrict__ dst6) {
    const float* ww[3] = {w4, w5, w6};
    f16* dd[3] = {dst4, dst5, dst6};
    const int RBt[3] = {0, 0, 1};
    const float* w = ww[blockIdx.x];
    f16* dst = dd[blockIdx.x];
    const int rb = RBt[blockIdx.x], sbk = 1 - rb;
    for (int i = threadIdx.x; i < 7 * 64 * 8; i += blockDim.x) {
        int g = i >> 9;
        int l = (i >> 3) & 63;
        int j = i & 7;
        int co = l & 15, sub = l >> 4;
        float v = 0.f;
        if (co < 8 && sub < 3) {
            int kw = sub;
            auto W_ = [&](int blk, int kh) {
                return softplusf(w[((co * 16 + blk * 8 + j) * 3 + kh) * 3 + kw]);
            };
            if (g < 3) v = W_(rb, g);
            else if (g == 3) v = W_(sbk, 0);
            else if (g == 4) v = W_(sbk, 1) + W_(sbk, 2);
            else if (g == 5) v = W_(sbk, 0) + W_(sbk, 1);
            else v = W_(sbk, 2);
        }
        dst[i] = (f16)v;
    }
}

// ---------------------------------------------------------------------------
// Layer 1 via MFMA (CIN=1): fp32 planar (x,c) -> f16 NHWC (xc, c).
// Epilogue algebra: den > 0 always (softplus weights > 0, c >= 0, center tap
// in-bounds), so (nom/(den+eps)+b)*(den/s) == (nom + b*den)/s exactly.
// ---------------------------------------------------------------------------
__global__ void __launch_bounds__(256) l1_mfma(
    const float* __restrict__ x0, const float* __restrict__ c0,
    const f16* __restrict__ afrag, const float* __restrict__ ssum,
    const float* __restrict__ bias,
    f16* __restrict__ xcout, f16* __restrict__ cout,
    int B, int H, int W, int CH) {
    const int lane = threadIdx.x & 63;
    const int wid = threadIdx.x >> 6;
    const int m = lane & 15, sub = lane >> 4;
    const int tilesW = (W + 15) >> 4;
    const int tw = blockIdx.x * 4 + wid;
    if (tw >= tilesW) return;
    const int w0 = tw << 4;
    const int b = blockIdx.z;
    const int h0 = blockIdx.y * CH;
    if (h0 >= H) return;

    v8h af = *(const v8h*)(afrag + lane * 8);

    float4 ssv = {1.f, 1.f, 1.f, 1.f}, bbv = {0.f, 0.f, 0.f, 0.f};
    if (sub < 2) {
        ssv = *(const float4*)(ssum + sub * 4);
        bbv = *(const float4*)(bias + sub * 4);
    }
    float rssv[4];
#pragma unroll
    for (int j = 0; j < 4; ++j) rssv[j] = __builtin_amdgcn_rcpf(((const float*)&ssv)[j]);

    const int HW = H * W;
    const float* cb = c0 + (size_t)b * HW;
    const float* xb = x0 + (size_t)b * HW;

    const unsigned W8u = (unsigned)W * 8;
    const unsigned bb8 = (unsigned)(b * H) * W8u;
    unsigned sbase = bb8 + (unsigned)h0 * W8u + (unsigned)(w0 + m) * 8 + sub * 4;

    auto epi = [&](const v4f& accd, const v4f& accn) {
        h4 xo8, c8;
#pragma unroll
        for (int j = 0; j < 4; ++j) {
            float d = accd[j];
            float cc = d * rssv[j];
            float xn = fmaf(((const float*)&bbv)[j], d, accn[j]) * rssv[j];
            c8[j] = (f16)cc;
            xo8[j] = (f16)xn;
        }
        *(h4*)(cout + sbase) = c8;
        *(h4*)(xcout + sbase) = xo8;
    };

    const int colr = w0 + m + sub - 2;
    const int cole = w0 + m + 2;

    const bool fast = (w0 >= 2) && (w0 + 17 < W) && (h0 >= 2) && (h0 + CH + 2 <= H);
    if (fast) {
        const float* crow = cb + (size_t)(h0 - 2) * W + colr;
        const float* xrow = xb + (size_t)(h0 - 2) * W + colr;
        f16 rc[5], rx[5];
#pragma unroll
        for (int t = 0; t < 4; ++t) {
            float cv = *crow, xv = *xrow;
            crow += W; xrow += W;
            rc[t] = (f16)cv;
            rx[t] = (f16)(xv * cv);
        }
        rc[4] = (f16)0; rx[4] = (f16)0;
        const float* c5p = cb + (size_t)(h0 + sub - 2) * W + cole;
        const float* x5p = xb + (size_t)(h0 + sub - 2) * W + cole;
        const float* c6p = cb + (size_t)(h0 + 2) * W + cole;
        const float* x6p = xb + (size_t)(h0 + 2) * W + cole;
        const bool st = (sub < 2);
        for (int hh = 0; hh < CH; hh += 5) {
#pragma unroll
            for (int p = 0; p < 5; ++p) {
                float cv = *crow, xv = *xrow;
                crow += W; xrow += W;
                rc[(p + 4) % 5] = (f16)cv;
                rx[(p + 4) % 5] = (f16)(xv * cv);
                float c5 = *c5p, x5 = *x5p;
                c5p += W; x5p += W;
                float c6 = *c6p, x6 = *x6p;
                c6p += W; x6p += W;
                f16 e5c = (f16)c5, e5x = (f16)(x5 * c5);
                f16 e6c = (f16)c6, e6x = (f16)(x6 * c6);
                v8h bc = {rc[p % 5], rc[(p + 1) % 5], rc[(p + 2) % 5],
                          rc[(p + 3) % 5], rc[(p + 4) % 5], e5c, e6c, (f16)0};
                v8h bx = {rx[p % 5], rx[(p + 1) % 5], rx[(p + 2) % 5],
                          rx[(p + 3) % 5], rx[(p + 4) % 5], e5x, e6x, (f16)0};
                v4f z = {0.f, 0.f, 0.f, 0.f};
                v4f accd = MFMA16(af, bc, z);
                v4f accn = MFMA16(af, bx, z);
                if (st) epi(accd, accn);
                sbase += W8u;
            }
        }
    } else {
        const bool okr = (colr >= 0) && (colr < W);
        const bool oke = (cole < W);
        const int colrc = min(max(colr, 0), W - 1);
        const int colec = min(cole, W - 1);
        const bool st = (sub < 2) && (w0 + m < W);
        for (int hh = 0; hh < CH; ++hh) {
            const int h = h0 + hh;
            if (h >= H) break;
            f16 vc[8], vx[8];
#pragma unroll
            for (int j = 0; j < 5; ++j) {
                int r = h + j - 2;
                bool ok = okr && (r >= 0) && (r < H);
                int rcl = min(max(r, 0), H - 1);
                float cv = cb[(size_t)rcl * W + colrc];
                float xv = xb[(size_t)rcl * W + colrc];
                vc[j] = ok ? (f16)cv : (f16)0;
                vx[j] = ok ? (f16)(xv * cv) : (f16)0;
            }
            {
                int r = h + sub - 2;
                bool ok = oke && (r >= 0) && (r < H);
                int rcl = min(max(r, 0), H - 1);
                float cv = cb[(size_t)rcl * W + colec];
                float xv = xb[(size_t)rcl * W + colec];
                vc[5] = ok ? (f16)cv : (f16)0;
                vx[5] = ok ? (f16)(xv * cv) : (f16)0;
            }
            {
                int r = h + 2;
                bool ok = oke && (r < H);
                int rcl = min(r, H - 1);
                float cv = cb[(size_t)rcl * W + colec];
                float xv = xb[(size_t)rcl * W + colec];
                vc[6] = ok ? (f16)cv : (f16)0;
                vx[6] = ok ? (f16)(xv * cv) : (f16)0;
            }
            vc[7] = (f16)0; vx[7] = (f16)0;
            v8h bc = {vc[0], vc[1], vc[2], vc[3], vc[4], vc[5], vc[6], vc[7]};
            v8h bx = {vx[0], vx[1], vx[2], vx[3], vx[4], vx[5], vx[6], vx[7]};
            v4f z = {0.f, 0.f, 0.f, 0.f};
            v4f accd = MFMA16(af, bc, z);
            v4f accn = MFMA16(af, bx, z);
            if (st) epi(accd, accn);
            sbase += W8u;
        }
    }
}

// ---------------------------------------------------------------------------
// Pool-gather NHWC, 2 output pixels per thread.
// ---------------------------------------------------------------------------
__global__ void __launch_bounds__(256) pool_nhwc(
    const f16* __restrict__ xc, const f16* __restrict__ c,
    f16* __restrict__ xo, f16* __restrict__ co_,
    int B, int H, int W) {
    int H2 = H >> 1, W2 = W >> 1, Wh = W2 >> 1;
    int idx = blockIdx.x * 256 + threadIdx.x;
    int total = B * H2 * Wh;
    if (idx >= total) return;
    int wo = (idx % Wh) * 2;
    int ho = (idx / Wh) % H2;
    int b = idx / (Wh * H2);
    unsigned base = (unsigned)(((b * H + 2 * ho) * W + 2 * wo) * 8);
    unsigned rb = (unsigned)(W * 8);
    v8h c0r[4], c1r[4], x0r[4], x1r[4];
#pragma unroll
    for (int i = 0; i < 4; ++i) {
        c0r[i] = *(const v8h*)(c + base + 8 * i);
        c1r[i] = *(const v8h*)(c + base + rb + 8 * i);
        x0r[i] = *(const v8h*)(xc + base + 8 * i);
        x1r[i] = *(const v8h*)(xc + base + rb + 8 * i);
    }
    unsigned oa = (unsigned)(((b * H2 + ho) * W2 + wo) * 8);
#pragma unroll
    for (int p = 0; p < 2; ++p) {
        v8h xr, cr;
#pragma unroll
        for (int e = 0; e < 8; ++e) {
            float b0 = (float)c0r[2 * p][e], b1 = (float)c0r[2 * p + 1][e];
            float b2 = (float)c1r[2 * p][e], b3 = (float)c1r[2 * p + 1][e];
            float cb = b0;
            float xv = (float)x0r[2 * p][e];
            if (b1 > cb) { cb = b1; xv = (float)x0r[2 * p + 1][e]; }
            if (b2 > cb) { cb = b2; xv = (float)x1r[2 * p][e]; }
            if (b3 > cb) { cb = b3; xv = (float)x1r[2 * p + 1][e]; }
            xr[e] = (f16)(xv * 0.25f);
            cr[e] = (f16)(cb * 0.25f);
        }
        *(v8h*)(xo + oa + p * 8) = xr;
        *(v8h*)(co_ + oa + p * 8) = cr;
    }
}

// ---------------------------------------------------------------------------
// Encoder nconv via MFMA. Fast path: 5-ring rotation + E5 cross-lane rotation
// (shfl executed with full exec, then per-lane select). 4 loads/row.
// Epilogue: rcp-free (den > 0; see l1 comment).
// CH multiple of 5.
// ---------------------------------------------------------------------------
__global__ void __launch_bounds__(256) enc5_mfma(
    const f16* __restrict__ xcin, const f16* __restrict__ cin,
    const f16* __restrict__ bfrag, const float* __restrict__ ssum,
    const float* __restrict__ bias,
    f16* __restrict__ xcout, f16* __restrict__ cout,
    int B, int H, int W, int CH) {
    const int lane = threadIdx.x & 63;
    const int wid = threadIdx.x >> 6;
    const int m = lane & 15, sub = lane >> 4;
    const int tilesW = (W + 15) >> 4;
    const int tw = blockIdx.x * 4 + wid;
    if (tw >= tilesW) return;
    const int w0 = tw << 4;
    const int b = blockIdx.z;
    const int h0 = blockIdx.y * CH;
    if (h0 >= H) return;

    v8h bf[7];
#pragma unroll
    for (int g = 0; g < 7; ++g)
        bf[g] = *(const v8h*)(bfrag + ((g << 6) + lane) * 8);

    float4 ssv = {1.f, 1.f, 1.f, 1.f}, bbv = {0.f, 0.f, 0.f, 0.f};
    if (sub < 2) {
        ssv = *(const float4*)(ssum + sub * 4);
        bbv = *(const float4*)(bias + sub * 4);
    }
    float rssv[4];
#pragma unroll
    for (int j = 0; j < 4; ++j) rssv[j] = __builtin_amdgcn_rcpf(((const float*)&ssv)[j]);

    const unsigned W8u = (unsigned)W * 8;
    const unsigned bb8 = (unsigned)(b * H) * W8u;
    unsigned sbase = bb8 + (unsigned)h0 * W8u + (unsigned)(w0 + m) * 8 + sub * 4;

    auto epi = [&](const v4f& accd, const v4f& accn) {
        h4 xo8, c8;
#pragma unroll
        for (int j = 0; j < 4; ++j) {
            float d = accd[j];
            float cc = d * rssv[j];
            float xn = fmaf(((const float*)&bbv)[j], d, accn[j]) * rssv[j];
            c8[j] = (f16)cc;
            xo8[j] = (f16)xn;
        }
        *(h4*)(cout + sbase) = c8;
        *(h4*)(xcout + sbase) = xo8;
    };

    const bool fast = (w0 >= 2) && (w0 + 17 < W) && (h0 >= 2) && (h0 + CH + 2 <= H);
    if (fast) {
        v8h Rc[5], Rx[5];
        unsigned aRot = bb8 + (unsigned)(h0 - 2) * W8u + (unsigned)(w0 + m + sub - 2) * 8;
#pragma unroll
        for (int t = 0; t < 4; ++t) {
            Rc[t] = *(const v8h*)(cin + aRot);
            Rx[t] = *(const v8h*)(xcin + aRot);
            aRot += W8u;
        }
        // E5 warm-up: row h0+sub-2, col w0+m+2
        unsigned aE5w = bb8 + (unsigned)(h0 + sub - 2) * W8u + (unsigned)(w0 + m + 2) * 8;
        v8h E5c = *(const v8h*)(cin + aE5w);
        v8h E5x = *(const v8h*)(xcin + aE5w);
        unsigned aE6 = bb8 + (unsigned)(h0 + 2) * W8u + (unsigned)(w0 + m + 2) * 8;
        const bool st = (sub < 2);
        for (int hh = 0; hh < CH; hh += 5) {
#pragma unroll
            for (int p = 0; p < 5; ++p) {
                Rc[(p + 4) % 5] = *(const v8h*)(cin + aRot);
                Rx[(p + 4) % 5] = *(const v8h*)(xcin + aRot);
                aRot += W8u;
                v8h e6c = *(const v8h*)(cin + aE6);
                v8h e6x = *(const v8h*)(xcin + aE6);
                aE6 += W8u;

                v4f accd = {0.f, 0.f, 0.f, 0.f}, accn = {0.f, 0.f, 0.f, 0.f};
#pragma unroll
                for (int g = 0; g < 5; ++g) {
                    accd = MFMA16(bf[g], Rc[(p + g) % 5], accd);
                    accn = MFMA16(bf[g], Rx[(p + g) % 5], accn);
                }
                accd = MFMA16(bf[5], E5c, accd);
                accn = MFMA16(bf[5], E5x, accn);
                accd = MFMA16(bf[6], e6c, accd);
                accn = MFMA16(bf[6], e6x, accn);

                // rotate E5 for next row: shfl with FULL exec, then select.
                v8h rotc = shfl_dn16(E5c);
                v8h rotx = shfl_dn16(E5x);
                E5c = (sub < 3) ? rotc : e6c;
                E5x = (sub < 3) ? rotx : e6x;

                if (st) epi(accd, accn);
                sbase += W8u;
            }
        }
    } else {
        const int cwr = w0 + m + sub - 2;
        const bool okc_r = (cwr >= 0) && (cwr < W);
        const unsigned a_rot = (unsigned)min(max(cwr, 0), W - 1) * 8;
        const int cwe = w0 + m + 2;
        const bool okc_e = cwe < W;
        const unsigned a_e = (unsigned)min(cwe, W - 1) * 8;
        const bool doStore = (sub < 2) && (w0 + m < W);

        v8h Rc[5], Rx[5];
#pragma unroll
        for (int t = 0; t < 4; ++t) {
            int r = h0 - 2 + t;
            bool ok = (r >= 0) && (r < H) && okc_r;
            unsigned a = bb8 + (unsigned)min(max(r, 0), H - 1) * W8u + a_rot;
            v8h pc = *(const v8h*)(cin + a);
            v8h px = *(const v8h*)(xcin + a);
            Rc[t] = ok ? pc : v8h_zero();
            Rx[t] = ok ? px : v8h_zero();
        }
        Rc[4] = v8h_zero();
        Rx[4] = v8h_zero();

        for (int hh = 0; hh < CH; hh += 5) {
#pragma unroll
            for (int p = 0; p < 5; ++p) {
                const int h = h0 + hh + p;
                {
                    int r = h + 2;
                    bool ok = (r < H) && okc_r;
                    unsigned a = bb8 + (unsigned)min(r, H - 1) * W8u + a_rot;
                    v8h pc = *(const v8h*)(cin + a);
                    v8h px = *(const v8h*)(xcin + a);
                    Rc[(p + 4) % 5] = ok ? pc : v8h_zero();
                    Rx[(p + 4) % 5] = ok ? px : v8h_zero();
                }
                v8h e5c, e5x;
                {
                    int r = h + sub - 2;
                    bool ok = (r >= 0) && (r < H) && okc_e;
                    unsigned a = bb8 + (unsigned)min(max(r, 0), H - 1) * W8u + a_e;
                    v8h pc = *(const v8h*)(cin + a);
                    v8h px = *(const v8h*)(xcin + a);
                    e5c = ok ? pc : v8h_zero();
                    e5x = ok ? px : v8h_zero();
                }
                v8h e6c, e6x;
                {
                    int r = h + 2;
                    bool ok = (r < H) && okc_e;
                    unsigned a = bb8 + (unsigned)min(r, H - 1) * W8u + a_e;
                    v8h pc = *(const v8h*)(cin + a);
                    v8h px = *(const v8h*)(xcin + a);
                    e6c = ok ? pc : v8h_zero();
                    e6x = ok ? px : v8h_zero();
                }

                v4f accd = {0.f, 0.f, 0.f, 0.f}, accn = {0.f, 0.f, 0.f, 0.f};
#pragma unroll
                for (int g = 0; g < 5; ++g) {
                    accd = MFMA16(bf[g], Rc[(p + g) % 5], accd);
                    accn = MFMA16(bf[g], Rx[(p + g) % 5], accn);
                }
                accd = MFMA16(bf[5], e5c, accd);
                accn = MFMA16(bf[5], e5x, accn);
                accd = MFMA16(bf[6], e6c, accd);
                accn = MFMA16(bf[6], e6x, accn);

                if (doStore && h < H) epi(accd, accn);
                sbase += W8u;
            }
        }
    }
}

// ---------------------------------------------------------------------------
// Decoder nconv via MFMA: R = same-res source (bf 0-2, rotating ring 3),
// S = half-res source with parity-folded weights (bf 3-6). CH multiple of 6,
// h0 even. FUSE7: fused final 1x1 nconv, fp32 1-ch outputs.
// Epilogue rcp-free except the single final per-pixel division.
// ---------------------------------------------------------------------------
template <bool FUSE7>
__global__ void __launch_bounds__(256) dec3_mfma(
    const f16* __restrict__ xcR, const f16* __restrict__ cR,
    const f16* __restrict__ xcS, const f16* __restrict__ cS,
    const f16* __restrict__ bfrag,
    const float* __restrict__ ssum, const float* __restrict__ bias,
    const float* __restrict__ wp7, const float* __restrict__ s7p,
    const float* __restrict__ b7p,
    f16* __restrict__ xcout, f16* __restrict__ ccout,
    float* __restrict__ xoutf, float* __restrict__ coutf,
    int B, int H, int W, int CH) {
    const int lane = threadIdx.x & 63;
    const int wid = threadIdx.x >> 6;
    const int m = lane & 15, sub = lane >> 4;
    const int tilesW = W >> 4;
    const int tw = blockIdx.x * 4 + wid;
    if (tw >= tilesW) return;
    const int w0 = tw << 4;
    const int b = blockIdx.z;
    const int h0 = blockIdx.y * CH;
    if (h0 >= H) return;

    v8h bf[7];
#pragma unroll
    for (int g = 0; g < 7; ++g)
        bf[g] = *(const v8h*)(bfrag + ((g << 6) + lane) * 8);

    const int cw = w0 + m + sub - 1;
    const bool okc = (cw >= 0) && (cw < W);
    const int cwc = min(max(cw, 0), W - 1);
    const unsigned aRc = (unsigned)cwc * 8;
    const unsigned aSc = (unsigned)(cwc >> 1) * 8;

    const int Hs = H >> 1, Ws = W >> 1;
    const unsigned WR8 = (unsigned)W * 8;
    const unsigned WS8 = (unsigned)Ws * 8;
    const unsigned bbR = (unsigned)(b * H) * WR8;
    const unsigned bbS = (unsigned)(b * Hs) * WS8;

    float4 ssv = {1.f, 1.f, 1.f, 1.f}, bbv = {0.f, 0.f, 0.f, 0.f};
    float4 w7v = {0.f, 0.f, 0.f, 0.f};
    if (sub < 2) {
        ssv = *(const float4*)(ssum + sub * 4);
        bbv = *(const float4*)(bias + sub * 4);
        if (FUSE7) w7v = *(const float4*)(wp7 + sub * 4);
    }
    float rssv[4];
#pragma unroll
    for (int j = 0; j < 4; ++j) rssv[j] = __builtin_amdgcn_rcpf(((const float*)&ssv)[j]);
    float rs7 = 0.f, b7v = 0.f;
    if (FUSE7) { rs7 = __builtin_amdgcn_rcpf(s7p[0]); b7v = b7p[0]; }

    unsigned sbase = bbR + (unsigned)h0 * WR8 + (unsigned)(w0 + m) * 8 + sub * 4;
    unsigned opix = (unsigned)(b * H + h0) * (unsigned)W + (unsigned)w0;

    auto epi = [&](const v4f& accd, const v4f& accn) {
        if constexpr (FUSE7) {
            float td = 0.f, tn = 0.f;
#pragma unroll
            for (int j = 0; j < 4; ++j) {
                float d = accd[j];  // exactly 0 for co>=8 (weights zeroed)
                float cc = d * rssv[j];
                float ocn = fmaf(((const float*)&bbv)[j], d, accn[j]) * rssv[j];
                td = fmaf(((const float*)&w7v)[j], cc, td);
                tn = fmaf(((const float*)&w7v)[j], ocn, tn);
            }
            td += __shfl_xor(td, 16);
            tn += __shfl_xor(tn, 16);
            td += __shfl_xor(td, 32);
            tn += __shfl_xor(tn, 32);
            if (sub == 0) {
                xoutf[opix + m] = tn * __builtin_amdgcn_rcpf(td + EPSV) + b7v;
            } else if (sub == 1) {
                coutf[opix + m] = td * rs7;
            }
        } else {
            if (sub < 2) {
                h4 xo8, c8;
#pragma unroll
                for (int j = 0; j < 4; ++j) {
                    float d = accd[j];
                    float cc = d * rssv[j];
                    float xn = fmaf(((const float*)&bbv)[j], d, accn[j]) * rssv[j];
                    c8[j] = (f16)cc;
                    xo8[j] = (f16)xn;
                }
                *(h4*)(ccout + sbase) = c8;
                *(h4*)(xcout + sbase) = xo8;
            }
        }
    };

    const bool fast = (w0 >= 1) && (w0 + 17 < W) && (h0 >= 2) && (h0 + CH + 1 <= H);
    if (fast) {
        v8h Rc_[3], Rx_[3], Sc_[3], Sx_[3];
        unsigned ar = bbR + (unsigned)(h0 - 1) * WR8 + aRc;
        Rc_[2] = *(const v8h*)(cR + ar); Rx_[2] = *(const v8h*)(xcR + ar); ar += WR8;
        Rc_[0] = *(const v8h*)(cR + ar); Rx_[0] = *(const v8h*)(xcR + ar); ar += WR8;
        const int k0 = h0 >> 1;
        unsigned as_ = bbS + (unsigned)(k0 - 1) * WS8 + aSc;
        Sc_[2] = *(const v8h*)(cS + as_); Sx_[2] = *(const v8h*)(xcS + as_); as_ += WS8;
        Sc_[0] = *(const v8h*)(cS + as_); Sx_[0] = *(const v8h*)(xcS + as_); as_ += WS8;

        for (int hh = 0; hh < CH; hh += 6) {
#pragma unroll
            for (int p = 0; p < 6; ++p) {
                const int j = p >> 1;
                Rc_[(p + 1) % 3] = *(const v8h*)(cR + ar);
                Rx_[(p + 1) % 3] = *(const v8h*)(xcR + ar);
                ar += WR8;
                if ((p & 1) == 0) {  // prefetch S row k+1
                    Sc_[(j + 1) % 3] = *(const v8h*)(cS + as_);
                    Sx_[(j + 1) % 3] = *(const v8h*)(xcS + as_);
                    as_ += WS8;
                }
                v4f accd = {0.f, 0.f, 0.f, 0.f}, accn = {0.f, 0.f, 0.f, 0.f};
#pragma unroll
                for (int g = 0; g < 3; ++g) {
                    accd = MFMA16(bf[g], Rc_[(p + g + 2) % 3], accd);
                    accn = MFMA16(bf[g], Rx_[(p + g + 2) % 3], accn);
                }
                if ((p & 1) == 0) {  // even h: W0 on S[k-1], W12 on S[k]
                    accd = MFMA16(bf[3], Sc_[(j + 2) % 3], accd);
                    accn = MFMA16(bf[3], Sx_[(j + 2) % 3], accn);
                    accd = MFMA16(bf[4], Sc_[j % 3], accd);
                    accn = MFMA16(bf[4], Sx_[j % 3], accn);
                } else {             // odd h: W01 on S[k], W2 on S[k+1]
                    accd = MFMA16(bf[5], Sc_[j % 3], accd);
                    accn = MFMA16(bf[5], Sx_[j % 3], accn);
                    accd = MFMA16(bf[6], Sc_[(j + 1) % 3], accd);
                    accn = MFMA16(bf[6], Sx_[(j + 1) % 3], accn);
                }
                epi(accd, accn);
                sbase += WR8;
                opix += W;
            }
        }
    } else {
        for (int hh = 0; hh < CH; ++hh) {
            const int h = h0 + hh;
            if (h >= H) break;
            const int k = h >> 1;
            const bool ev = (h & 1) == 0;
            v4f accd = {0.f, 0.f, 0.f, 0.f}, accn = {0.f, 0.f, 0.f, 0.f};
#pragma unroll
            for (int g = 0; g < 3; ++g) {
                int r = h + g - 1;
                bool ok = okc && (r >= 0) && (r < H);
                unsigned a = bbR + (unsigned)min(max(r, 0), H - 1) * WR8 + aRc;
                v8h pc = *(const v8h*)(cR + a);
                v8h px = *(const v8h*)(xcR + a);
                if (!ok) { pc = v8h_zero(); px = v8h_zero(); }
                accd = MFMA16(bf[g], pc, accd);
                accn = MFMA16(bf[g], px, accn);
            }
            {
                int rs = ev ? (k - 1) : k;
                bool ok = okc && (!ev || (h >= 1));
                unsigned a = bbS + (unsigned)min(max(rs, 0), Hs - 1) * WS8 + aSc;
                v8h pc = *(const v8h*)(cS + a);
                v8h px = *(const v8h*)(xcS + a);
                if (!ok) { pc = v8h_zero(); px = v8h_zero(); }
                v8h wA = ev ? bf[3] : bf[5];
                accd = MFMA16(wA, pc, accd);
                accn = MFMA16(wA, px, accn);
            }
            {
                int rs = ev ? k : (k + 1);
                bool ok = okc && (ev || (h + 1 < H));
                unsigned a = bbS + (unsigned)min(max(rs, 0), Hs - 1) * WS8 + aSc;
                v8h pc = *(const v8h*)(cS + a);
                v8h px = *(const v8h*)(xcS + a);
                if (!ok) { pc = v8h_zero(); px = v8h_zero(); }
                v8h wB = ev ? bf[4] : bf[6];
                accd = MFMA16(wB, pc, accd);
                accn = MFMA16(wB, px, accn);
            }
            epi(accd, accn);
            sbase += WR8;
            opix += W;
        }
    }
}

// ---------------------------------------------------------------------------
extern "C" void kernel_launch(void* const* d_in, const int* in_sizes, int n_in,
                              void* d_out, int out_size, void* d_ws, size_t ws_size,
                              hipStream_t stream) {
    const float* x0 = (const float*)d_in[0];
    const float* c0 = (const float*)d_in[1];
    const float* w1 = (const float*)d_in[2];
    const float* b1 = (const float*)d_in[3];
    const float* w2 = (const float*)d_in[4];
    const float* b2 = (const float*)d_in[5];
    const float* w3 = (const float*)d_in[6];
    const float* b3 = (const float*)d_in[7];
    const float* w4 = (const float*)d_in[8];
    const float* b4 = (const float*)d_in[9];
    const float* w5 = (const float*)d_in[10];
    const float* b5 = (const float*)d_in[11];
    const float* w6 = (const float*)d_in[12];
    const float* b6 = (const float*)d_in[13];
    const float* w7 = (const float*)d_in[14];
    const float* b7 = (const float*)d_in[15];

    const int B = 8, H = 352, W = 1216;
    const int H2 = 176, W2 = 608, H4 = 88, W4 = 304, H8 = 44, W8 = 152;
    const size_t F   = (size_t)64 * H * W;
    const size_t H2s = (size_t)64 * H2 * W2;
    const size_t Qs  = (size_t)64 * H4 * W4;
    const size_t Es  = (size_t)64 * H8 * W8;

    const size_t needH = 4 * F * sizeof(f16) + 28672;
    const size_t needFull = 4 * F * sizeof(f16) + 65536;
    if (ws_size < needH) return;
    const bool FULL = (ws_size >= needFull);  // ws_size fixed -> deterministic

    f16* ws = (f16*)d_ws;
    f16* P0x = ws;            // full-res NHWC (xc, c), persists to final decoder
    f16* P0c = ws + F;
    f16* Ux  = ws + 2 * F;    // full-res ping
    f16* Uc  = ws + 3 * F;
    f16* D1x = ws + 2 * F;    // half-res set aliases region 2 (4*H2s == F)
    f16* D1c = D1x + H2s;
    f16* D2x = D1c + H2s;
    f16* D2c = D2x + H2s;
    f16* Q1x = ws + 3 * F;    // quarter + eighth alias region 3
    f16* Q1c = Q1x + Qs;
    f16* Q2x = Q1c + Qs;
    f16* Q2c = Q2x + Qs;
    f16* E1x = Q2c + Qs;
    f16* E1c = E1x + Es;
    f16* E2x = E1c + Es;
    f16* E2c = E2x + Es;

    char* tail = (char*)d_ws + 4 * F * sizeof(f16);
    float* WT = (float*)tail;
    f16* BF2 = (f16*)(tail + 2048);
    f16* BF3 = (f16*)(tail + 9216);
    f16* BF1 = (f16*)(tail + 16384);
    // DF placement: FULL -> dedicated tail; fallback -> region-3 slack.
    f16* DF4 = FULL ? (f16*)(tail + 17408) : (ws + 3 * F + 16777216);
    f16* DF5 = DF4 + 3584;
    f16* DF6 = DF5 + 3584;

    const float* s1 = WT + 200;
    const float* s2 = WT + 208;
    const float* s3 = WT + 216;
    const float* s4 = WT + 224;
    const float* s5 = WT + 232;
    const float* s6 = WT + 240;
    const float* s7 = WT + 248;
    const float* wp7 = WT + 256;

    prep_misc<<<10, 256, 0, stream>>>(w1, w2, w3, w4, w5, w6, w7, WT, BF2, BF3, BF1);
    if (FULL)
        pack_dec_frag<<<3, 256, 0, stream>>>(w4, w5, w6, DF4, DF5, DF6);

    auto nb = [](size_t n) { return (int)((n + 255) / 256); };
    // enc/l1 grids: x = ceil(tilesW/4), y = ceil(H/CH), CH % 5 == 0, z = B.
    const dim3 geF(19, 18, 8);   // CH=20
    const dim3 geH(10, 18, 8);   // CH=10
    const dim3 geQ(5, 9, 8);     // CH=10
    const dim3 geE(3, 9, 8);     // CH=5
    // dec grids: CH % 6 == 0 (h0 even).
    const dim3 gdF(19, 30, 8);   // CH=12
    const dim3 gdH(10, 15, 8);   // CH=12
    const dim3 gdQ(5, 8, 8);     // CH=12

    // Encoder
    l1_mfma<<<geF, 256, 0, stream>>>(x0, c0, BF1, s1, b1, P0x, P0c, B, H, W, 20);
    enc5_mfma<<<geF, 256, 0, stream>>>(P0x, P0c, BF2, s2, b2, Ux, Uc, B, H, W, 20);
    enc5_mfma<<<geF, 256, 0, stream>>>(Ux, Uc, BF3, s3, b3, P0x, P0c, B, H, W, 20);
    if (!FULL)  // region-3 DF slack only safe now (Uc dead)
        pack_dec_frag<<<3, 256, 0, stream>>>(w4, w5, w6, DF4, DF5, DF6);
    pool_nhwc<<<nb((size_t)B * H2 * (W2 / 2)), 256, 0, stream>>>(P0x, P0c, D1x, D1c, B, H, W);
    enc5_mfma<<<geH, 256, 0, stream>>>(D1x, D1c, BF2, s2, b2, D2x, D2c, B, H2, W2, 10);
    enc5_mfma<<<geH, 256, 0, stream>>>(D2x, D2c, BF3, s3, b3, D1x, D1c, B, H2, W2, 10);
    pool_nhwc<<<nb((size_t)B * H4 * (W4 / 2)), 256, 0, stream>>>(D1x, D1c, Q1x, Q1c, B, H2, W2);
    enc5_mfma<<<geQ, 256, 0, stream>>>(Q1x, Q1c, BF2, s2, b2, Q2x, Q2c, B, H4, W4, 10);
    pool_nhwc<<<nb((size_t)B * H8 * (W8 / 2)), 256, 0, stream>>>(Q2x, Q2c, E1x, E1c, B, H4, W4);
    enc5_mfma<<<geE, 256, 0, stream>>>(E1x, E1c, BF2, s2, b2, E2x, E2c, B, H8, W8, 5);

    // Decoder: R = same-res source (per pack RB), S = half-res (parity-folded).
    dec3_mfma<false><<<gdQ, 256, 0, stream>>>(
        Q2x, Q2c, E2x, E2c, DF4, s4, b4, WT, WT, WT,
        Q1x, Q1c, (float*)nullptr, (float*)nullptr, B, H4, W4, 12);
    dec3_mfma<false><<<gdH, 256, 0, stream>>>(
        D1x, D1c, Q1x, Q1c, DF5, s5, b5, WT, WT, WT,
        D2x, D2c, (float*)nullptr, (float*)nullptr, B, H2, W2, 12);

    float* outx = (float*)d_out;
    float* outc = outx + (size_t)B * H * W;
    dec3_mfma<true><<<gdF, 256, 0, stream>>>(
        P0x, P0c, D2x, D2c, DF6, s6, b6, wp7, s7, b7,
        (f16*)nullptr, (f16*)nullptr, outx, outc, B, H, W, 12);
}